// Round 1
// baseline (9589.907 us; speedup 1.0000x reference)
//
#include <hip/hip_runtime.h>
#include <math.h>

#define NROWS 16384
#define DIN   384
#define DIM   512
#define KSEL  6
#define NSPLIT 4
#define COLS_PER_SPLIT (NROWS / NSPLIT)   // 4096
#define ATT_SCALE 0.044194173824159216f   // 512^-0.5

static __device__ __forceinline__ float lrelu_f(float v) {
  return v > 0.f ? v : 0.01f * v;
}

// ---------------------------------------------------------------------------
// Generic tiled f32 GEMM: C = act(A[M,Kd] @ W[Kd,Nc] + bias), optional +=
// BM=BN=64, BK=16, 256 threads, 4x4 per-thread microtile.
// ---------------------------------------------------------------------------
template<int ACT, int ACCUM>
__global__ __launch_bounds__(256)
void gemm_f32(const float* __restrict__ A, const float* __restrict__ W,
              const float* __restrict__ bias, float* __restrict__ C,
              int M, int Kd, int Nc) {
  __shared__ float As[64][17];
  __shared__ float Ws[16][64];
  const int tid = threadIdx.x;
  const int tx = tid & 15, ty = tid >> 4;
  const int rowBase = blockIdx.y * 64, colBase = blockIdx.x * 64;
  float acc[4][4];
  #pragma unroll
  for (int i = 0; i < 4; i++)
    #pragma unroll
    for (int j = 0; j < 4; j++) acc[i][j] = 0.f;

  const int rA = tid >> 2, cA = (tid & 3) * 4;   // A tile 64x16
  const int kW = tid >> 4, cW = (tid & 15) * 4;  // W tile 16x64

  for (int kc = 0; kc < Kd; kc += 16) {
    float4 va = *(const float4*)(A + (size_t)(rowBase + rA) * Kd + kc + cA);
    As[rA][cA + 0] = va.x; As[rA][cA + 1] = va.y;
    As[rA][cA + 2] = va.z; As[rA][cA + 3] = va.w;
    *(float4*)&Ws[kW][cW] =
        *(const float4*)(W + (size_t)(kc + kW) * Nc + colBase + cW);
    __syncthreads();
    #pragma unroll
    for (int kk = 0; kk < 16; ++kk) {
      float4 b = *(const float4*)&Ws[kk][tx * 4];
      float a0 = As[ty * 4 + 0][kk], a1 = As[ty * 4 + 1][kk];
      float a2 = As[ty * 4 + 2][kk], a3 = As[ty * 4 + 3][kk];
      acc[0][0] += a0 * b.x; acc[0][1] += a0 * b.y;
      acc[0][2] += a0 * b.z; acc[0][3] += a0 * b.w;
      acc[1][0] += a1 * b.x; acc[1][1] += a1 * b.y;
      acc[1][2] += a1 * b.z; acc[1][3] += a1 * b.w;
      acc[2][0] += a2 * b.x; acc[2][1] += a2 * b.y;
      acc[2][2] += a2 * b.z; acc[2][3] += a2 * b.w;
      acc[3][0] += a3 * b.x; acc[3][1] += a3 * b.y;
      acc[3][2] += a3 * b.z; acc[3][3] += a3 * b.w;
    }
    __syncthreads();
  }
  #pragma unroll
  for (int j = 0; j < 4; j++) {
    int col = colBase + tx * 4 + j;
    float bj = bias[col];
    #pragma unroll
    for (int i = 0; i < 4; i++) {
      int row = rowBase + ty * 4 + i;
      float v = acc[i][j] + bj;
      if (ACT == 1) v = lrelu_f(v);
      size_t o = (size_t)row * Nc + col;
      if (ACCUM) C[o] += v; else C[o] = v;
    }
  }
}

// ---------------------------------------------------------------------------
// Column sums of H[NROWS][DIM]: partial over 512-row chunks, then finalize.
// ---------------------------------------------------------------------------
__global__ __launch_bounds__(256)
void colsum_partial(const float* __restrict__ H, float* __restrict__ part) {
  // grid (8, 32): x = 64-col group, y = 512-row chunk
  int col = blockIdx.x * 64 + (threadIdx.x & 63);
  int sub = threadIdx.x >> 6;  // 0..3
  int rEnd = blockIdx.y * 512 + 512;
  float s = 0.f;
  for (int r = blockIdx.y * 512 + sub; r < rEnd; r += 4)
    s += H[(size_t)r * DIM + col];
  __shared__ float sh[4][64];
  sh[sub][threadIdx.x & 63] = s;
  __syncthreads();
  if (threadIdx.x < 64) {
    float tot = sh[0][threadIdx.x] + sh[1][threadIdx.x] +
                sh[2][threadIdx.x] + sh[3][threadIdx.x];
    part[(size_t)blockIdx.y * DIM + col] = tot;
  }
}

__global__ void finalize_mean(const float* __restrict__ part,
                              float* __restrict__ mean) {
  int c = threadIdx.x;  // 512 threads
  float s = 0.f;
  for (int j = 0; j < 32; j++) s += part[j * DIM + c];
  mean[c] = s * (1.0f / NROWS);
}

__global__ __launch_bounds__(256)
void h_fix(float* __restrict__ H, const float* __restrict__ mean) {
  int idx = blockIdx.x * 256 + threadIdx.x;  // float4 index
  int c = (idx * 4) & (DIM - 1);
  float4 v = ((float4*)H)[idx];
  v.x = (v.x + mean[c + 0]) * 0.5f;
  v.y = (v.y + mean[c + 1]) * 0.5f;
  v.z = (v.z + mean[c + 2]) * 0.5f;
  v.w = (v.w + mean[c + 3]) * 0.5f;
  ((float4*)H)[idx] = v;
}

// ---------------------------------------------------------------------------
// Fused attn-logit GEMM + streaming per-row top-6 (per column split).
// Block: 64 rows x (4096-col split). Tiles: 64x128, K-chunks of 32.
// Per-thread 4x8 microtile; cols tx+16j (2-way LDS banks on b128 reads).
// ---------------------------------------------------------------------------
__global__ __launch_bounds__(256)
void attn_topk(const float* __restrict__ EH, const float* __restrict__ ET,
               float* __restrict__ TWp, int* __restrict__ TIp) {
  __shared__ float Ach[64][36];    // rows x k(32)+pad
  __shared__ float Bch[128][36];   // cols x k(32)+pad
  __shared__ float Ssh[64][129];   // score tile + pad
  const int tid = threadIdx.x;
  const int tx = tid & 15, ty = tid >> 4;
  const int rowBase = blockIdx.x * 64;
  const int split = blockIdx.y;
  const int colSplitBase = split * COLS_PER_SPLIT;

  float tv[KSEL]; int tix[KSEL];
  #pragma unroll
  for (int k = 0; k < KSEL; k++) { tv[k] = -INFINITY; tix[k] = 0; }

  const int rA = tid >> 2, k0A = (tid & 3) * 8;   // A stage: 2 float4 each
  const int cB = tid >> 1, k0B = (tid & 1) * 16;  // B stage: 4 float4 each

  for (int ct = 0; ct < COLS_PER_SPLIT / 128; ++ct) {
    const int colBase = colSplitBase + ct * 128;
    float acc[4][8];
    #pragma unroll
    for (int i = 0; i < 4; i++)
      #pragma unroll
      for (int j = 0; j < 8; j++) acc[i][j] = 0.f;

    for (int kc = 0; kc < DIM / 32; ++kc) {
      // stage A (scaled) and B
      {
        const float* src = EH + (size_t)(rowBase + rA) * DIM + kc * 32 + k0A;
        float4 u0 = ((const float4*)src)[0];
        float4 u1 = ((const float4*)src)[1];
        u0.x *= ATT_SCALE; u0.y *= ATT_SCALE; u0.z *= ATT_SCALE; u0.w *= ATT_SCALE;
        u1.x *= ATT_SCALE; u1.y *= ATT_SCALE; u1.z *= ATT_SCALE; u1.w *= ATT_SCALE;
        *(float4*)&Ach[rA][k0A]     = u0;
        *(float4*)&Ach[rA][k0A + 4] = u1;
        const float* srcb = ET + (size_t)(colBase + cB) * DIM + kc * 32 + k0B;
        *(float4*)&Bch[cB][k0B + 0]  = ((const float4*)srcb)[0];
        *(float4*)&Bch[cB][k0B + 4]  = ((const float4*)srcb)[1];
        *(float4*)&Bch[cB][k0B + 8]  = ((const float4*)srcb)[2];
        *(float4*)&Bch[cB][k0B + 12] = ((const float4*)srcb)[3];
      }
      __syncthreads();
      #pragma unroll
      for (int kk = 0; kk < 32; kk += 4) {
        float4 av[4]; float4 bv[8];
        #pragma unroll
        for (int i = 0; i < 4; i++)
          av[i] = *(const float4*)&Ach[ty * 4 + i][kk];
        #pragma unroll
        for (int j = 0; j < 8; j++)
          bv[j] = *(const float4*)&Bch[tx + 16 * j][kk];
        #pragma unroll
        for (int i = 0; i < 4; i++)
          #pragma unroll
          for (int j = 0; j < 8; j++)
            acc[i][j] += av[i].x * bv[j].x + av[i].y * bv[j].y +
                         av[i].z * bv[j].z + av[i].w * bv[j].w;
      }
      __syncthreads();
    }
    // spill tile to LDS, scan rows for top-k
    #pragma unroll
    for (int i = 0; i < 4; i++)
      #pragma unroll
      for (int j = 0; j < 8; j++)
        Ssh[ty * 4 + i][tx + 16 * j] = acc[i][j];
    __syncthreads();
    if (tid < 64) {
      #pragma unroll 1
      for (int c = 0; c < 128; ++c) {
        float v = Ssh[tid][c];
        if (v > tv[KSEL - 1]) {
          tv[5] = v; tix[5] = colBase + c;
          // static bubble (strict >: ties keep earlier index first)
          if (tv[5] > tv[4]) { float t = tv[4]; tv[4] = tv[5]; tv[5] = t;
                               int ti = tix[4]; tix[4] = tix[5]; tix[5] = ti; }
          if (tv[4] > tv[3]) { float t = tv[3]; tv[3] = tv[4]; tv[4] = t;
                               int ti = tix[3]; tix[3] = tix[4]; tix[4] = ti; }
          if (tv[3] > tv[2]) { float t = tv[2]; tv[2] = tv[3]; tv[3] = t;
                               int ti = tix[2]; tix[2] = tix[3]; tix[3] = ti; }
          if (tv[2] > tv[1]) { float t = tv[1]; tv[1] = tv[2]; tv[2] = t;
                               int ti = tix[1]; tix[1] = tix[2]; tix[2] = ti; }
          if (tv[1] > tv[0]) { float t = tv[0]; tv[0] = tv[1]; tv[1] = t;
                               int ti = tix[0]; tix[0] = tix[1]; tix[1] = ti; }
        }
      }
    }
    __syncthreads();
  }
  if (tid < 64) {
    size_t o = ((size_t)split * NROWS + rowBase + tid) * KSEL;
    #pragma unroll
    for (int k = 0; k < KSEL; k++) { TWp[o + k] = tv[k]; TIp[o + k] = tix[k]; }
  }
}

// Merge NSPLIT per-split top-6 lists into global top-6 (value desc, idx asc).
__global__ __launch_bounds__(256)
void topk_merge(const float* __restrict__ TWp, const int* __restrict__ TIp,
                float* __restrict__ TW, int* __restrict__ TI) {
  int row = blockIdx.x * 256 + threadIdx.x;
  float tv[KSEL]; int tix[KSEL];
  #pragma unroll
  for (int k = 0; k < KSEL; k++) { tv[k] = -INFINITY; tix[k] = 0x7fffffff; }
  #pragma unroll
  for (int s = 0; s < NSPLIT; s++) {
    size_t o = ((size_t)s * NROWS + row) * KSEL;
    #pragma unroll
    for (int k = 0; k < KSEL; k++) {
      float cv = TWp[o + k]; int ci = TIp[o + k];
      bool better5 = (cv > tv[5]) || (cv == tv[5] && ci < tix[5]);
      if (better5) {
        tv[5] = cv; tix[5] = ci;
        if ((tv[5] > tv[4]) || (tv[5] == tv[4] && tix[5] < tix[4])) {
          float t = tv[4]; tv[4] = tv[5]; tv[5] = t;
          int ti = tix[4]; tix[4] = tix[5]; tix[5] = ti; }
        if ((tv[4] > tv[3]) || (tv[4] == tv[3] && tix[4] < tix[3])) {
          float t = tv[3]; tv[3] = tv[4]; tv[4] = t;
          int ti = tix[3]; tix[3] = tix[4]; tix[4] = ti; }
        if ((tv[3] > tv[2]) || (tv[3] == tv[2] && tix[3] < tix[2])) {
          float t = tv[2]; tv[2] = tv[3]; tv[3] = t;
          int ti = tix[2]; tix[2] = tix[3]; tix[3] = ti; }
        if ((tv[2] > tv[1]) || (tv[2] == tv[1] && tix[2] < tix[1])) {
          float t = tv[1]; tv[1] = tv[2]; tv[2] = t;
          int ti = tix[1]; tix[1] = tix[2]; tix[2] = ti; }
        if ((tv[1] > tv[0]) || (tv[1] == tv[0] && tix[1] < tix[0])) {
          float t = tv[0]; tv[0] = tv[1]; tv[1] = t;
          int ti = tix[0]; tix[0] = tix[1]; tix[1] = ti; }
      }
    }
  }
  size_t o = (size_t)row * KSEL;
  #pragma unroll
  for (int k = 0; k < KSEL; k++) { TW[o + k] = tv[k]; TI[o + k] = tix[k]; }
}

// ---------------------------------------------------------------------------
// Per-row neighbor aggregation. One 64-lane wave per row.
// Writes SIN = e_h + e_Nh, BIN = e_h * e_Nh (BIN overwrites EH buffer: each
// wave only reads its OWN e_h row before writing; gathers come from ET).
// ---------------------------------------------------------------------------
__global__ __launch_bounds__(256)
void neighbor_kernel(const float* __restrict__ EH, const float* __restrict__ ET,
                     const float* __restrict__ TW, const int* __restrict__ TI,
                     float* __restrict__ SIN, float* __restrict__ BIN) {
  const int lane = threadIdx.x & 63;
  const int row = blockIdx.x * 4 + (threadIdx.x >> 6);
  const float* eh = EH + (size_t)row * DIM;
  float ehv[8];
  #pragma unroll
  for (int u = 0; u < 8; u++) ehv[u] = eh[u * 64 + lane];
  float tw[KSEL]; int ti[KSEL];
  #pragma unroll
  for (int k = 0; k < KSEL; k++) {
    tw[k] = TW[(size_t)row * KSEL + k];
    ti[k] = TI[(size_t)row * KSEL + k];
  }
  // p = softmax(topk_w)
  float m = tw[0];
  #pragma unroll
  for (int k = 1; k < KSEL; k++) m = fmaxf(m, tw[k]);
  float p[KSEL], ps = 0.f;
  #pragma unroll
  for (int k = 0; k < KSEL; k++) { p[k] = expf(tw[k] - m); ps += p[k]; }
  float inv = 1.f / ps;
  #pragma unroll
  for (int k = 0; k < KSEL; k++) p[k] *= inv;

  float nb[KSEL][8];
  float kaw[KSEL];
  #pragma unroll
  for (int k = 0; k < KSEL; k++) {
    const float* et = ET + (size_t)ti[k] * DIM;
    float snb = 0.f, sg = 0.f;
    #pragma unroll
    for (int u = 0; u < 8; u++) {
      float nbv = et[u * 64 + lane];
      nb[k][u] = nbv;
      float ehr = p[k] * nbv + (1.f - p[k]) * ehv[u];
      float g = tanhf(ehv[u] + ehr);
      snb += nbv; sg += g;
    }
    #pragma unroll
    for (int off = 32; off > 0; off >>= 1) {
      snb += __shfl_xor(snb, off);
      sg  += __shfl_xor(sg, off);
    }
    kaw[k] = snb * sg;
  }
  // ka_p = softmax(kaw)
  float km = kaw[0];
  #pragma unroll
  for (int k = 1; k < KSEL; k++) km = fmaxf(km, kaw[k]);
  float kp[KSEL], ks = 0.f;
  #pragma unroll
  for (int k = 0; k < KSEL; k++) { kp[k] = expf(kaw[k] - km); ks += kp[k]; }
  float kinv = 1.f / ks;
  #pragma unroll
  for (int k = 0; k < KSEL; k++) kp[k] *= kinv;

  #pragma unroll
  for (int u = 0; u < 8; u++) {
    float enh = 0.f;
    #pragma unroll
    for (int k = 0; k < KSEL; k++) enh += kp[k] * nb[k][u];
    size_t o = (size_t)row * DIM + u * 64 + lane;
    SIN[o] = ehv[u] + enh;
    BIN[o] = ehv[u] * enh;
  }
}

// a[row] = dot(hidden[row][0:256], att2_w) + att2_b  (one wave per row)
__global__ __launch_bounds__(256)
void att2_kernel(const float* __restrict__ HID, const float* __restrict__ w2,
                 const float* __restrict__ b2, float* __restrict__ ASC) {
  const int lane = threadIdx.x & 63;
  const int row = blockIdx.x * 4 + (threadIdx.x >> 6);
  float4 hv = ((const float4*)(HID + (size_t)row * 256))[lane];
  float4 wv = ((const float4*)w2)[lane];
  float s = hv.x * wv.x + hv.y * wv.y + hv.z * wv.z + hv.w * wv.w;
  #pragma unroll
  for (int off = 32; off > 0; off >>= 1) s += __shfl_xor(s, off);
  if (lane == 0) ASC[row] = s + b2[0];
}

// global max / sum-exp of ASC[NROWS]  -> stats[0]=max, stats[1]=sumexp
__global__ __launch_bounds__(1024)
void areduce(const float* __restrict__ ASC, float* __restrict__ stats) {
  __shared__ float sm[1024];
  int t = threadIdx.x;
  float m = -INFINITY;
  for (int i = t; i < NROWS; i += 1024) m = fmaxf(m, ASC[i]);
  sm[t] = m; __syncthreads();
  for (int s = 512; s > 0; s >>= 1) {
    if (t < s) sm[t] = fmaxf(sm[t], sm[t + s]);
    __syncthreads();
  }
  float mx = sm[0]; __syncthreads();
  float sum = 0.f;
  for (int i = t; i < NROWS; i += 1024) sum += expf(ASC[i] - mx);
  sm[t] = sum; __syncthreads();
  for (int s = 512; s > 0; s >>= 1) {
    if (t < s) sm[t] += sm[t + s];
    __syncthreads();
  }
  if (t == 0) { stats[0] = mx; stats[1] = sm[0]; }
}

// pooled partials: part[chunk][d] = sum_{rows in chunk} exp(a-mx)*emb[r][d]
__global__ __launch_bounds__(256)
void pooled_partial(const float* __restrict__ EMB, const float* __restrict__ ASC,
                    const float* __restrict__ stats, float* __restrict__ part) {
  int col = blockIdx.x * 64 + (threadIdx.x & 63);
  int sub = threadIdx.x >> 6;
  float mx = stats[0];
  int rEnd = blockIdx.y * 512 + 512;
  float s = 0.f;
  for (int r = blockIdx.y * 512 + sub; r < rEnd; r += 4)
    s += expf(ASC[r] - mx) * EMB[(size_t)r * DIM + col];
  __shared__ float sh[4][64];
  sh[sub][threadIdx.x & 63] = s;
  __syncthreads();
  if (threadIdx.x < 64) {
    float tot = sh[0][threadIdx.x] + sh[1][threadIdx.x] +
                sh[2][threadIdx.x] + sh[3][threadIdx.x];
    part[(size_t)blockIdx.y * DIM + col] = tot;
  }
}

// final: pooled -> LayerNorm -> fc -> softmax. Single block, 512 threads.
__global__ __launch_bounds__(512)
void final_kernel(const float* __restrict__ part, const float* __restrict__ stats,
                  const float* __restrict__ ln_g, const float* __restrict__ ln_b,
                  const float* __restrict__ fc_w, const float* __restrict__ fc_b,
                  float* __restrict__ out) {
  __shared__ float sh[512];
  int t = threadIdx.x;
  float s = 0.f;
  for (int j = 0; j < 32; j++) s += part[j * DIM + t];
  float pooled = s / stats[1];
  sh[t] = pooled; __syncthreads();
  for (int off = 256; off > 0; off >>= 1) {
    if (t < off) sh[t] += sh[t + off];
    __syncthreads();
  }
  float mu = sh[0] * (1.f / DIM); __syncthreads();
  float dv = pooled - mu;
  sh[t] = dv * dv; __syncthreads();
  for (int off = 256; off > 0; off >>= 1) {
    if (t < off) sh[t] += sh[t + off];
    __syncthreads();
  }
  float var = sh[0] * (1.f / DIM); __syncthreads();
  float normed = dv * rsqrtf(var + 1e-5f) * ln_g[t] + ln_b[t];
  sh[t] = normed * fc_w[t * 2 + 0]; __syncthreads();
  for (int off = 256; off > 0; off >>= 1) {
    if (t < off) sh[t] += sh[t + off];
    __syncthreads();
  }
  float l0 = sh[0] + fc_b[0]; __syncthreads();
  sh[t] = normed * fc_w[t * 2 + 1]; __syncthreads();
  for (int off = 256; off > 0; off >>= 1) {
    if (t < off) sh[t] += sh[t + off];
    __syncthreads();
  }
  float l1 = sh[0] + fc_b[1];
  if (t == 0) {
    float mm = fmaxf(l0, l1);
    float e0 = expf(l0 - mm), e1 = expf(l1 - mm);
    float si = 1.f / (e0 + e1);
    out[0] = l0; out[1] = l1; out[2] = e0 * si; out[3] = e1 * si;
  }
}

// ---------------------------------------------------------------------------
extern "C" void kernel_launch(void* const* d_in, const int* in_sizes, int n_in,
                              void* d_out, int out_size, void* d_ws, size_t ws_size,
                              hipStream_t stream) {
  (void)in_sizes; (void)n_in; (void)out_size; (void)ws_size;
  const float* x      = (const float*)d_in[0];
  const float* fc1_w  = (const float*)d_in[1];
  const float* fc1_b  = (const float*)d_in[2];
  const float* wh_w   = (const float*)d_in[3];
  const float* wh_b   = (const float*)d_in[4];
  const float* wt_w   = (const float*)d_in[5];
  const float* wt_b   = (const float*)d_in[6];
  const float* lin1_w = (const float*)d_in[7];
  const float* lin1_b = (const float*)d_in[8];
  const float* lin2_w = (const float*)d_in[9];
  const float* lin2_b = (const float*)d_in[10];
  const float* att1_w = (const float*)d_in[11];
  const float* att1_b = (const float*)d_in[12];
  const float* att2_w = (const float*)d_in[13];
  const float* att2_b = (const float*)d_in[14];
  const float* ln_g   = (const float*)d_in[15];
  const float* ln_b   = (const float*)d_in[16];
  const float* fc_w   = (const float*)d_in[17];
  const float* fc_b   = (const float*)d_in[18];
  float* out = (float*)d_out;

  char* ws = (char*)d_ws;
  const size_t SZ_BUF = (size_t)NROWS * DIM * 4;   // 33,554,432
  float* B0   = (float*)(ws);                       // h / s_in / hidden
  float* B1   = (float*)(ws + SZ_BUF);              // e_h / b_in
  float* B2   = (float*)(ws + 2 * SZ_BUF);          // e_t / emb
  float* TWp  = (float*)(ws + 3 * SZ_BUF);
  int*   TIp  = (int*)  (ws + 3 * SZ_BUF + 1572864);
  float* TW   = (float*)(ws + 3 * SZ_BUF + 2 * 1572864);
  int*   TI   = (int*)  (ws + 3 * SZ_BUF + 2 * 1572864 + 393216);
  float* part = (float*)(ws + 3 * SZ_BUF + 2 * 1572864 + 2 * 393216);
  float* mean = (float*)(ws + 3 * SZ_BUF + 2 * 1572864 + 2 * 393216 + 65536);
  float* ascr = (float*)(ws + 3 * SZ_BUF + 2 * 1572864 + 2 * 393216 + 65536 + 2048);
  float* stats= (float*)(ws + 3 * SZ_BUF + 2 * 1572864 + 2 * 393216 + 65536 + 2048 + 65536);

  // 1. h0 = lrelu(x @ fc1_w + fc1_b)
  gemm_f32<1,0><<<dim3(DIM/64, NROWS/64), 256, 0, stream>>>(x, fc1_w, fc1_b, B0,
                                                            NROWS, DIN, DIM);
  // 2-4. column mean, h = (h0 + mean)*0.5
  colsum_partial<<<dim3(8, 32), 256, 0, stream>>>(B0, part);
  finalize_mean<<<1, 512, 0, stream>>>(part, mean);
  h_fix<<<(NROWS * DIM / 4) / 256, 256, 0, stream>>>(B0, mean);
  // 5-6. e_h, e_t
  gemm_f32<0,0><<<dim3(DIM/64, NROWS/64), 256, 0, stream>>>(B0, wh_w, wh_b, B1,
                                                            NROWS, DIM, DIM);
  gemm_f32<0,0><<<dim3(DIM/64, NROWS/64), 256, 0, stream>>>(B0, wt_w, wt_b, B2,
                                                            NROWS, DIM, DIM);
  // 7. fused attn-logit + top-k (per split), then merge
  attn_topk<<<dim3(NROWS/64, NSPLIT), 256, 0, stream>>>(B1, B2, TWp, TIp);
  topk_merge<<<NROWS/256, 256, 0, stream>>>(TWp, TIp, TW, TI);
  // 8. neighbor aggregation -> s_in (B0), b_in (B1)
  neighbor_kernel<<<NROWS/4, 256, 0, stream>>>(B1, B2, TW, TI, B0, B1);
  // 9-10. emb = lrelu(s_in@lin1) + lrelu(b_in@lin2)  -> B2 (e_t now dead)
  gemm_f32<1,0><<<dim3(DIM/64, NROWS/64), 256, 0, stream>>>(B0, lin1_w, lin1_b, B2,
                                                            NROWS, DIM, DIM);
  gemm_f32<1,1><<<dim3(DIM/64, NROWS/64), 256, 0, stream>>>(B1, lin2_w, lin2_b, B2,
                                                            NROWS, DIM, DIM);
  // 11. hidden = lrelu(emb@att1) -> B0
  gemm_f32<1,0><<<dim3(256/64, NROWS/64), 256, 0, stream>>>(B2, att1_w, att1_b, B0,
                                                            NROWS, DIM, 256);
  // 12. a = hidden@att2 + b
  att2_kernel<<<NROWS/4, 256, 0, stream>>>(B0, att2_w, att2_b, ascr);
  // 13. softmax stats over a
  areduce<<<1, 1024, 0, stream>>>(ascr, stats);
  // 14. pooled partials (reuse `part`)
  pooled_partial<<<dim3(8, 32), 256, 0, stream>>>(B2, ascr, stats, part);
  // 15. LN + fc + softmax -> out
  final_kernel<<<1, 512, 0, stream>>>(part, stats, ln_g, ln_b, fc_w, fc_b, out);
}

// Round 2
// 1762.972 us; speedup vs baseline: 5.4396x; 5.4396x over previous
//
#include <hip/hip_runtime.h>
#include <math.h>

#define NROWS 16384
#define DIN   384
#define DIM   512
#define KSEL  6
#define NSPLIT 4
#define COLS_PER_SPLIT (NROWS / NSPLIT)   // 4096
#define ATT_SCALE 0.044194173824159216f   // 512^-0.5

typedef unsigned short u16;
typedef __attribute__((ext_vector_type(8))) short bf16x8;
typedef __attribute__((ext_vector_type(4))) float f32x4;

static __device__ __forceinline__ float lrelu_f(float v) {
  return v > 0.f ? v : 0.01f * v;
}

static __device__ __forceinline__ u16 f2bf(float f) {  // RNE f32->bf16
  unsigned u = __float_as_uint(f);
  unsigned r = (u + 0x7FFFu + ((u >> 16) & 1u)) >> 16;
  return (u16)r;
}

// ---------------------------------------------------------------------------
// Generic tiled f32 GEMM: C = act(A[M,Kd] @ W[Kd,Nc] + bias), optional +=
// ---------------------------------------------------------------------------
template<int ACT, int ACCUM>
__global__ __launch_bounds__(256)
void gemm_f32(const float* __restrict__ A, const float* __restrict__ W,
              const float* __restrict__ bias, float* __restrict__ C,
              int M, int Kd, int Nc) {
  __shared__ float As[64][17];
  __shared__ float Ws[16][64];
  const int tid = threadIdx.x;
  const int tx = tid & 15, ty = tid >> 4;
  const int rowBase = blockIdx.y * 64, colBase = blockIdx.x * 64;
  float acc[4][4];
  #pragma unroll
  for (int i = 0; i < 4; i++)
    #pragma unroll
    for (int j = 0; j < 4; j++) acc[i][j] = 0.f;

  const int rA = tid >> 2, cA = (tid & 3) * 4;
  const int kW = tid >> 4, cW = (tid & 15) * 4;

  for (int kc = 0; kc < Kd; kc += 16) {
    float4 va = *(const float4*)(A + (size_t)(rowBase + rA) * Kd + kc + cA);
    As[rA][cA + 0] = va.x; As[rA][cA + 1] = va.y;
    As[rA][cA + 2] = va.z; As[rA][cA + 3] = va.w;
    *(float4*)&Ws[kW][cW] =
        *(const float4*)(W + (size_t)(kc + kW) * Nc + colBase + cW);
    __syncthreads();
    #pragma unroll
    for (int kk = 0; kk < 16; ++kk) {
      float4 b = *(const float4*)&Ws[kk][tx * 4];
      float a0 = As[ty * 4 + 0][kk], a1 = As[ty * 4 + 1][kk];
      float a2 = As[ty * 4 + 2][kk], a3 = As[ty * 4 + 3][kk];
      acc[0][0] += a0 * b.x; acc[0][1] += a0 * b.y;
      acc[0][2] += a0 * b.z; acc[0][3] += a0 * b.w;
      acc[1][0] += a1 * b.x; acc[1][1] += a1 * b.y;
      acc[1][2] += a1 * b.z; acc[1][3] += a1 * b.w;
      acc[2][0] += a2 * b.x; acc[2][1] += a2 * b.y;
      acc[2][2] += a2 * b.z; acc[2][3] += a2 * b.w;
      acc[3][0] += a3 * b.x; acc[3][1] += a3 * b.y;
      acc[3][2] += a3 * b.z; acc[3][3] += a3 * b.w;
    }
    __syncthreads();
  }
  #pragma unroll
  for (int j = 0; j < 4; j++) {
    int col = colBase + tx * 4 + j;
    float bj = bias[col];
    #pragma unroll
    for (int i = 0; i < 4; i++) {
      int row = rowBase + ty * 4 + i;
      float v = acc[i][j] + bj;
      if (ACT == 1) v = lrelu_f(v);
      size_t o = (size_t)row * Nc + col;
      if (ACCUM) C[o] += v; else C[o] = v;
    }
  }
}

// ---------------------------------------------------------------------------
__global__ __launch_bounds__(256)
void colsum_partial(const float* __restrict__ H, float* __restrict__ part) {
  int col = blockIdx.x * 64 + (threadIdx.x & 63);
  int sub = threadIdx.x >> 6;
  int rEnd = blockIdx.y * 512 + 512;
  float s = 0.f;
  for (int r = blockIdx.y * 512 + sub; r < rEnd; r += 4)
    s += H[(size_t)r * DIM + col];
  __shared__ float sh[4][64];
  sh[sub][threadIdx.x & 63] = s;
  __syncthreads();
  if (threadIdx.x < 64) {
    float tot = sh[0][threadIdx.x] + sh[1][threadIdx.x] +
                sh[2][threadIdx.x] + sh[3][threadIdx.x];
    part[(size_t)blockIdx.y * DIM + col] = tot;
  }
}

__global__ void finalize_mean(const float* __restrict__ part,
                              float* __restrict__ mean) {
  int c = threadIdx.x;
  float s = 0.f;
  for (int j = 0; j < 32; j++) s += part[j * DIM + c];
  mean[c] = s * (1.0f / NROWS);
}

__global__ __launch_bounds__(256)
void h_fix(float* __restrict__ H, const float* __restrict__ mean) {
  int idx = blockIdx.x * 256 + threadIdx.x;
  int c = (idx * 4) & (DIM - 1);
  float4 v = ((float4*)H)[idx];
  v.x = (v.x + mean[c + 0]) * 0.5f;
  v.y = (v.y + mean[c + 1]) * 0.5f;
  v.z = (v.z + mean[c + 2]) * 0.5f;
  v.w = (v.w + mean[c + 3]) * 0.5f;
  ((float4*)H)[idx] = v;
}

// ---------------------------------------------------------------------------
// f32 -> bf16 conversion: EHb = bf16(EH*SCALE), ETb = bf16(ET). 8 elem/thread.
// ---------------------------------------------------------------------------
__global__ __launch_bounds__(256)
void conv_bf16(const float* __restrict__ EH, const float* __restrict__ ET,
               u16* __restrict__ EHb, u16* __restrict__ ETb) {
  int i = blockIdx.x * 256 + threadIdx.x;   // chunk of 8, < NROWS*DIM/8
  const float4* pe = (const float4*)EH + (size_t)i * 2;
  float4 a = pe[0], b = pe[1];
  uint4 o;
  o.x = f2bf(a.x * ATT_SCALE) | ((unsigned)f2bf(a.y * ATT_SCALE) << 16);
  o.y = f2bf(a.z * ATT_SCALE) | ((unsigned)f2bf(a.w * ATT_SCALE) << 16);
  o.z = f2bf(b.x * ATT_SCALE) | ((unsigned)f2bf(b.y * ATT_SCALE) << 16);
  o.w = f2bf(b.z * ATT_SCALE) | ((unsigned)f2bf(b.w * ATT_SCALE) << 16);
  ((uint4*)EHb)[i] = o;
  const float4* pt = (const float4*)ET + (size_t)i * 2;
  a = pt[0]; b = pt[1];
  o.x = f2bf(a.x) | ((unsigned)f2bf(a.y) << 16);
  o.y = f2bf(a.z) | ((unsigned)f2bf(a.w) << 16);
  o.z = f2bf(b.x) | ((unsigned)f2bf(b.y) << 16);
  o.w = f2bf(b.z) | ((unsigned)f2bf(b.w) << 16);
  ((uint4*)ETb)[i] = o;
}

// ---------------------------------------------------------------------------
// MFMA attn-logit GEMM + streaming per-row top-6 (per column split).
// Block: 256 thr = 4 waves; tile 64 rows x 256 cols; K-chunk 64.
// Wave w owns cols [64w,64w+64): 4x4 frags of mfma_f32_16x16x32_bf16.
// Scores spilled in two 64x128 f32 halves into the B-staging LDS (union),
// scanned by all threads (4 segs/row). 48KB LDS -> 3 blocks/CU.
// ---------------------------------------------------------------------------
#define TINSERT(vv, cc) do { float v_ = (vv); \
  if (v_ > tv[5]) { tv[5] = v_; tix[5] = (cc); \
    if (tv[5] > tv[4]) { float t=tv[4];tv[4]=tv[5];tv[5]=t; int q=tix[4];tix[4]=tix[5];tix[5]=q; } \
    if (tv[4] > tv[3]) { float t=tv[3];tv[3]=tv[4];tv[4]=t; int q=tix[3];tix[3]=tix[4];tix[4]=q; } \
    if (tv[3] > tv[2]) { float t=tv[2];tv[2]=tv[3];tv[3]=t; int q=tix[2];tix[2]=tix[3];tix[3]=q; } \
    if (tv[2] > tv[1]) { float t=tv[1];tv[1]=tv[2];tv[2]=t; int q=tix[1];tix[1]=tix[2];tix[2]=q; } \
    if (tv[1] > tv[0]) { float t=tv[0];tv[0]=tv[1];tv[1]=t; int q=tix[0];tix[0]=tix[1];tix[1]=q; } \
  } } while (0)

__global__ __launch_bounds__(256, 3)
void attn_topk_mfma(const u16* __restrict__ EHb, const u16* __restrict__ ETb,
                    float* __restrict__ TWp, int* __restrict__ TIp) {
  __shared__ char ldsA[12288];                 // Ash  | merge buffers
  __shared__ char ldsB[36864];                 // Bsh  | score tile
  u16  (*Ash)[72]  = (u16 (*)[72])ldsA;        // 64x72 bf16 (pad 8 -> 144B rows)
  u16  (*Bsh)[72]  = (u16 (*)[72])ldsB;        // 256x72 bf16
  float (*Ssh)[132] = (float (*)[132])ldsB;    // 64x132 f32 (33792B <= 36864)
  float* MrgV = (float*)ldsA;                  // 64*4*6 f32 = 6144B
  int*   MrgI = (int*)(ldsA + 6144);           // 6144B

  const int tid = threadIdx.x;
  const int w = tid >> 6, l = tid & 63;
  const int lr = l & 15, lg = l >> 4;
  const int rowBase = blockIdx.x * 64;
  const int split = blockIdx.y;
  const int scanRow = tid >> 2, seg = tid & 3;

  float tv[KSEL]; int tix[KSEL];
  #pragma unroll
  for (int k = 0; k < KSEL; k++) { tv[k] = -INFINITY; tix[k] = 0; }

  for (int ct = 0; ct < COLS_PER_SPLIT / 256; ++ct) {
    const int colBase = split * COLS_PER_SPLIT + ct * 256;
    f32x4 acc[4][4];
    #pragma unroll
    for (int i = 0; i < 4; i++)
      #pragma unroll
      for (int j = 0; j < 4; j++) acc[i][j] = (f32x4){0.f, 0.f, 0.f, 0.f};

    for (int kc = 0; kc < DIM / 64; ++kc) {
      const int k0 = kc * 64;
      #pragma unroll
      for (int p = 0; p < 2; ++p) {            // stage A: 64 rows x 64 k
        int u = tid + 256 * p;
        int ar = u >> 3, k8 = (u & 7) * 8;
        uint4 d = *(const uint4*)(EHb + (size_t)(rowBase + ar) * DIM + k0 + k8);
        *(uint4*)&Ash[ar][k8] = d;
      }
      #pragma unroll
      for (int p = 0; p < 8; ++p) {            // stage B: 256 rows x 64 k
        int u = tid + 256 * p;
        int br = u >> 3, k8 = (u & 7) * 8;
        uint4 d = *(const uint4*)(ETb + (size_t)(colBase + br) * DIM + k0 + k8);
        *(uint4*)&Bsh[br][k8] = d;
      }
      __syncthreads();
      #pragma unroll
      for (int ks = 0; ks < 2; ++ks) {
        const int koff = ks * 32 + lg * 8;
        bf16x8 av[4], bv[4];
        #pragma unroll
        for (int i = 0; i < 4; i++)
          av[i] = *(const bf16x8*)&Ash[16 * i + lr][koff];
        #pragma unroll
        for (int j = 0; j < 4; j++)
          bv[j] = *(const bf16x8*)&Bsh[64 * w + 16 * j + lr][koff];
        #pragma unroll
        for (int i = 0; i < 4; i++)
          #pragma unroll
          for (int j = 0; j < 4; j++)
            acc[i][j] = __builtin_amdgcn_mfma_f32_16x16x32_bf16(
                av[i], bv[j], acc[i][j], 0, 0, 0);
      }
      __syncthreads();
    }
    // spill + scan in two 128-col passes (Ssh aliases Bsh)
    #pragma unroll
    for (int pass = 0; pass < 2; ++pass) {
      if ((w >> 1) == pass) {
        int cb = 64 * (w & 1);
        #pragma unroll
        for (int i = 0; i < 4; i++)
          #pragma unroll
          for (int j = 0; j < 4; j++)
            #pragma unroll
            for (int r = 0; r < 4; r++)
              Ssh[16 * i + 4 * lg + r][cb + 16 * j + lr] = acc[i][j][r];
      }
      __syncthreads();
      int gcb = colBase + pass * 128;
      #pragma unroll
      for (int i = 0; i < 8; i++) {
        float4 v4 = *(const float4*)&Ssh[scanRow][seg * 4 + 16 * i];
        int c0 = gcb + seg * 4 + 16 * i;
        TINSERT(v4.x, c0 + 0); TINSERT(v4.y, c0 + 1);
        TINSERT(v4.z, c0 + 2); TINSERT(v4.w, c0 + 3);
      }
      __syncthreads();
    }
  }
  // merge the 4 per-seg lists per row (tie -> lowest index)
  {
    int base = (scanRow * 4 + seg) * 6;
    #pragma unroll
    for (int k = 0; k < KSEL; k++) { MrgV[base + k] = tv[k]; MrgI[base + k] = tix[k]; }
  }
  __syncthreads();
  if (tid < 64) {
    int mb = tid * 24;
    unsigned used = 0;
    float ov[KSEL]; int oi[KSEL];
    #pragma unroll
    for (int s = 0; s < KSEL; ++s) {
      float bvv = -INFINITY; int bi = 0x7fffffff; int be = 0;
      for (int e = 0; e < 24; ++e) {
        if (used & (1u << e)) continue;
        float v = MrgV[mb + e]; int ix = MrgI[mb + e];
        if (v > bvv || (v == bvv && ix < bi)) { bvv = v; bi = ix; be = e; }
      }
      used |= 1u << be;
      ov[s] = bvv; oi[s] = bi;
    }
    size_t o = ((size_t)split * NROWS + rowBase + tid) * KSEL;
    #pragma unroll
    for (int k = 0; k < KSEL; k++) { TWp[o + k] = ov[k]; TIp[o + k] = oi[k]; }
  }
}

// Merge NSPLIT per-split top-6 lists into global top-6 (value desc, idx asc).
__global__ __launch_bounds__(256)
void topk_merge(const float* __restrict__ TWp, const int* __restrict__ TIp,
                float* __restrict__ TW, int* __restrict__ TI) {
  int row = blockIdx.x * 256 + threadIdx.x;
  float tv[KSEL]; int tix[KSEL];
  #pragma unroll
  for (int k = 0; k < KSEL; k++) { tv[k] = -INFINITY; tix[k] = 0x7fffffff; }
  #pragma unroll
  for (int s = 0; s < NSPLIT; s++) {
    size_t o = ((size_t)s * NROWS + row) * KSEL;
    #pragma unroll
    for (int k = 0; k < KSEL; k++) {
      float cv = TWp[o + k]; int ci = TIp[o + k];
      bool better5 = (cv > tv[5]) || (cv == tv[5] && ci < tix[5]);
      if (better5) {
        tv[5] = cv; tix[5] = ci;
        if ((tv[5] > tv[4]) || (tv[5] == tv[4] && tix[5] < tix[4])) {
          float t = tv[4]; tv[4] = tv[5]; tv[5] = t;
          int ti = tix[4]; tix[4] = tix[5]; tix[5] = ti; }
        if ((tv[4] > tv[3]) || (tv[4] == tv[3] && tix[4] < tix[3])) {
          float t = tv[3]; tv[3] = tv[4]; tv[4] = t;
          int ti = tix[3]; tix[3] = tix[4]; tix[4] = ti; }
        if ((tv[3] > tv[2]) || (tv[3] == tv[2] && tix[3] < tix[2])) {
          float t = tv[2]; tv[2] = tv[3]; tv[3] = t;
          int ti = tix[2]; tix[2] = tix[3]; tix[3] = ti; }
        if ((tv[2] > tv[1]) || (tv[2] == tv[1] && tix[2] < tix[1])) {
          float t = tv[1]; tv[1] = tv[2]; tv[2] = t;
          int ti = tix[1]; tix[1] = tix[2]; tix[2] = ti; }
        if ((tv[1] > tv[0]) || (tv[1] == tv[0] && tix[1] < tix[0])) {
          float t = tv[0]; tv[0] = tv[1]; tv[1] = t;
          int ti = tix[0]; tix[0] = tix[1]; tix[1] = ti; }
      }
    }
  }
  size_t o = (size_t)row * KSEL;
  #pragma unroll
  for (int k = 0; k < KSEL; k++) { TW[o + k] = tv[k]; TI[o + k] = tix[k]; }
}

// ---------------------------------------------------------------------------
__global__ __launch_bounds__(256)
void neighbor_kernel(const float* __restrict__ EH, const float* __restrict__ ET,
                     const float* __restrict__ TW, const int* __restrict__ TI,
                     float* __restrict__ SIN, float* __restrict__ BIN) {
  const int lane = threadIdx.x & 63;
  const int row = blockIdx.x * 4 + (threadIdx.x >> 6);
  const float* eh = EH + (size_t)row * DIM;
  float ehv[8];
  #pragma unroll
  for (int u = 0; u < 8; u++) ehv[u] = eh[u * 64 + lane];
  float tw[KSEL]; int ti[KSEL];
  #pragma unroll
  for (int k = 0; k < KSEL; k++) {
    tw[k] = TW[(size_t)row * KSEL + k];
    ti[k] = TI[(size_t)row * KSEL + k];
  }
  float m = tw[0];
  #pragma unroll
  for (int k = 1; k < KSEL; k++) m = fmaxf(m, tw[k]);
  float p[KSEL], ps = 0.f;
  #pragma unroll
  for (int k = 0; k < KSEL; k++) { p[k] = expf(tw[k] - m); ps += p[k]; }
  float inv = 1.f / ps;
  #pragma unroll
  for (int k = 0; k < KSEL; k++) p[k] *= inv;

  float nb[KSEL][8];
  float kaw[KSEL];
  #pragma unroll
  for (int k = 0; k < KSEL; k++) {
    const float* et = ET + (size_t)ti[k] * DIM;
    float snb = 0.f, sg = 0.f;
    #pragma unroll
    for (int u = 0; u < 8; u++) {
      float nbv = et[u * 64 + lane];
      nb[k][u] = nbv;
      float ehr = p[k] * nbv + (1.f - p[k]) * ehv[u];
      float g = tanhf(ehv[u] + ehr);
      snb += nbv; sg += g;
    }
    #pragma unroll
    for (int off = 32; off > 0; off >>= 1) {
      snb += __shfl_xor(snb, off);
      sg  += __shfl_xor(sg, off);
    }
    kaw[k] = snb * sg;
  }
  float km = kaw[0];
  #pragma unroll
  for (int k = 1; k < KSEL; k++) km = fmaxf(km, kaw[k]);
  float kp[KSEL], ks = 0.f;
  #pragma unroll
  for (int k = 0; k < KSEL; k++) { kp[k] = expf(kaw[k] - km); ks += kp[k]; }
  float kinv = 1.f / ks;
  #pragma unroll
  for (int k = 0; k < KSEL; k++) kp[k] *= kinv;

  #pragma unroll
  for (int u = 0; u < 8; u++) {
    float enh = 0.f;
    #pragma unroll
    for (int k = 0; k < KSEL; k++) enh += kp[k] * nb[k][u];
    size_t o = (size_t)row * DIM + u * 64 + lane;
    SIN[o] = ehv[u] + enh;
    BIN[o] = ehv[u] * enh;
  }
}

__global__ __launch_bounds__(256)
void att2_kernel(const float* __restrict__ HID, const float* __restrict__ w2,
                 const float* __restrict__ b2, float* __restrict__ ASC) {
  const int lane = threadIdx.x & 63;
  const int row = blockIdx.x * 4 + (threadIdx.x >> 6);
  float4 hv = ((const float4*)(HID + (size_t)row * 256))[lane];
  float4 wv = ((const float4*)w2)[lane];
  float s = hv.x * wv.x + hv.y * wv.y + hv.z * wv.z + hv.w * wv.w;
  #pragma unroll
  for (int off = 32; off > 0; off >>= 1) s += __shfl_xor(s, off);
  if (lane == 0) ASC[row] = s + b2[0];
}

__global__ __launch_bounds__(1024)
void areduce(const float* __restrict__ ASC, float* __restrict__ stats) {
  __shared__ float sm[1024];
  int t = threadIdx.x;
  float m = -INFINITY;
  for (int i = t; i < NROWS; i += 1024) m = fmaxf(m, ASC[i]);
  sm[t] = m; __syncthreads();
  for (int s = 512; s > 0; s >>= 1) {
    if (t < s) sm[t] = fmaxf(sm[t], sm[t + s]);
    __syncthreads();
  }
  float mx = sm[0]; __syncthreads();
  float sum = 0.f;
  for (int i = t; i < NROWS; i += 1024) sum += expf(ASC[i] - mx);
  sm[t] = sum; __syncthreads();
  for (int s = 512; s > 0; s >>= 1) {
    if (t < s) sm[t] += sm[t + s];
    __syncthreads();
  }
  if (t == 0) { stats[0] = mx; stats[1] = sm[0]; }
}

__global__ __launch_bounds__(256)
void pooled_partial(const float* __restrict__ EMB, const float* __restrict__ ASC,
                    const float* __restrict__ stats, float* __restrict__ part) {
  int col = blockIdx.x * 64 + (threadIdx.x & 63);
  int sub = threadIdx.x >> 6;
  float mx = stats[0];
  int rEnd = blockIdx.y * 512 + 512;
  float s = 0.f;
  for (int r = blockIdx.y * 512 + sub; r < rEnd; r += 4)
    s += expf(ASC[r] - mx) * EMB[(size_t)r * DIM + col];
  __shared__ float sh[4][64];
  sh[sub][threadIdx.x & 63] = s;
  __syncthreads();
  if (threadIdx.x < 64) {
    float tot = sh[0][threadIdx.x] + sh[1][threadIdx.x] +
                sh[2][threadIdx.x] + sh[3][threadIdx.x];
    part[(size_t)blockIdx.y * DIM + col] = tot;
  }
}

__global__ __launch_bounds__(512)
void final_kernel(const float* __restrict__ part, const float* __restrict__ stats,
                  const float* __restrict__ ln_g, const float* __restrict__ ln_b,
                  const float* __restrict__ fc_w, const float* __restrict__ fc_b,
                  float* __restrict__ out) {
  __shared__ float sh[512];
  int t = threadIdx.x;
  float s = 0.f;
  for (int j = 0; j < 32; j++) s += part[j * DIM + t];
  float pooled = s / stats[1];
  sh[t] = pooled; __syncthreads();
  for (int off = 256; off > 0; off >>= 1) {
    if (t < off) sh[t] += sh[t + off];
    __syncthreads();
  }
  float mu = sh[0] * (1.f / DIM); __syncthreads();
  float dv = pooled - mu;
  sh[t] = dv * dv; __syncthreads();
  for (int off = 256; off > 0; off >>= 1) {
    if (t < off) sh[t] += sh[t + off];
    __syncthreads();
  }
  float var = sh[0] * (1.f / DIM); __syncthreads();
  float normed = dv * rsqrtf(var + 1e-5f) * ln_g[t] + ln_b[t];
  sh[t] = normed * fc_w[t * 2 + 0]; __syncthreads();
  for (int off = 256; off > 0; off >>= 1) {
    if (t < off) sh[t] += sh[t + off];
    __syncthreads();
  }
  float l0 = sh[0] + fc_b[0]; __syncthreads();
  sh[t] = normed * fc_w[t * 2 + 1]; __syncthreads();
  for (int off = 256; off > 0; off >>= 1) {
    if (t < off) sh[t] += sh[t + off];
    __syncthreads();
  }
  float l1 = sh[0] + fc_b[1];
  if (t == 0) {
    float mm = fmaxf(l0, l1);
    float e0 = expf(l0 - mm), e1 = expf(l1 - mm);
    float si = 1.f / (e0 + e1);
    out[0] = l0; out[1] = l1; out[2] = e0 * si; out[3] = e1 * si;
  }
}

// ---------------------------------------------------------------------------
extern "C" void kernel_launch(void* const* d_in, const int* in_sizes, int n_in,
                              void* d_out, int out_size, void* d_ws, size_t ws_size,
                              hipStream_t stream) {
  (void)in_sizes; (void)n_in; (void)out_size; (void)ws_size;
  const float* x      = (const float*)d_in[0];
  const float* fc1_w  = (const float*)d_in[1];
  const float* fc1_b  = (const float*)d_in[2];
  const float* wh_w   = (const float*)d_in[3];
  const float* wh_b   = (const float*)d_in[4];
  const float* wt_w   = (const float*)d_in[5];
  const float* wt_b   = (const float*)d_in[6];
  const float* lin1_w = (const float*)d_in[7];
  const float* lin1_b = (const float*)d_in[8];
  const float* lin2_w = (const float*)d_in[9];
  const float* lin2_b = (const float*)d_in[10];
  const float* att1_w = (const float*)d_in[11];
  const float* att1_b = (const float*)d_in[12];
  const float* att2_w = (const float*)d_in[13];
  const float* att2_b = (const float*)d_in[14];
  const float* ln_g   = (const float*)d_in[15];
  const float* ln_b   = (const float*)d_in[16];
  const float* fc_w   = (const float*)d_in[17];
  const float* fc_b   = (const float*)d_in[18];
  float* out = (float*)d_out;

  char* ws = (char*)d_ws;
  const size_t SZ_BUF = (size_t)NROWS * DIM * 4;   // 33,554,432
  float* B0   = (float*)(ws);                       // h / s_in / hidden
  float* B1   = (float*)(ws + SZ_BUF);              // e_h / b_in
  float* B2   = (float*)(ws + 2 * SZ_BUF);          // e_t / emb
  float* TWp  = (float*)(ws + 3 * SZ_BUF);
  int*   TIp  = (int*)  (ws + 3 * SZ_BUF + 1572864);
  float* TW   = (float*)(ws + 3 * SZ_BUF + 2 * 1572864);
  int*   TI   = (int*)  (ws + 3 * SZ_BUF + 2 * 1572864 + 393216);
  float* part = (float*)(ws + 3 * SZ_BUF + 2 * 1572864 + 2 * 393216);
  float* mean = (float*)(ws + 3 * SZ_BUF + 2 * 1572864 + 2 * 393216 + 65536);
  float* ascr = (float*)(ws + 3 * SZ_BUF + 2 * 1572864 + 2 * 393216 + 65536 + 2048);
  float* stats= (float*)(ws + 3 * SZ_BUF + 2 * 1572864 + 2 * 393216 + 65536 + 2048 + 65536);
  u16*   EHb  = (u16*)  (ws + 104732672);           // 16 MiB
  u16*   ETb  = (u16*)  (ws + 104732672 + 16777216);// 16 MiB (end ~132 MB)

  // 1. h0 = lrelu(x @ fc1_w + fc1_b)
  gemm_f32<1,0><<<dim3(DIM/64, NROWS/64), 256, 0, stream>>>(x, fc1_w, fc1_b, B0,
                                                            NROWS, DIN, DIM);
  // 2-4. column mean, h = (h0 + mean)*0.5
  colsum_partial<<<dim3(8, 32), 256, 0, stream>>>(B0, part);
  finalize_mean<<<1, 512, 0, stream>>>(part, mean);
  h_fix<<<(NROWS * DIM / 4) / 256, 256, 0, stream>>>(B0, mean);
  // 5-6. e_h, e_t
  gemm_f32<0,0><<<dim3(DIM/64, NROWS/64), 256, 0, stream>>>(B0, wh_w, wh_b, B1,
                                                            NROWS, DIM, DIM);
  gemm_f32<0,0><<<dim3(DIM/64, NROWS/64), 256, 0, stream>>>(B0, wt_w, wt_b, B2,
                                                            NROWS, DIM, DIM);
  // 7. bf16 conversion (EHb has SCALE folded in)
  conv_bf16<<<NROWS * DIM / 8 / 256, 256, 0, stream>>>(B1, B2, EHb, ETb);
  // 8. fused MFMA attn-logit + top-k (per split), then merge
  attn_topk_mfma<<<dim3(NROWS/64, NSPLIT), 256, 0, stream>>>(EHb, ETb, TWp, TIp);
  topk_merge<<<NROWS/256, 256, 0, stream>>>(TWp, TIp, TW, TI);
  // 9. neighbor aggregation -> s_in (B0), b_in (B1)
  neighbor_kernel<<<NROWS/4, 256, 0, stream>>>(B1, B2, TW, TI, B0, B1);
  // 10-11. emb = lrelu(s_in@lin1) + lrelu(b_in@lin2)  -> B2
  gemm_f32<1,0><<<dim3(DIM/64, NROWS/64), 256, 0, stream>>>(B0, lin1_w, lin1_b, B2,
                                                            NROWS, DIM, DIM);
  gemm_f32<1,1><<<dim3(DIM/64, NROWS/64), 256, 0, stream>>>(B1, lin2_w, lin2_b, B2,
                                                            NROWS, DIM, DIM);
  // 12. hidden = lrelu(emb@att1) -> B0
  gemm_f32<1,0><<<dim3(256/64, NROWS/64), 256, 0, stream>>>(B2, att1_w, att1_b, B0,
                                                            NROWS, DIM, 256);
  // 13. a = hidden@att2 + b
  att2_kernel<<<NROWS/4, 256, 0, stream>>>(B0, att2_w, att2_b, ascr);
  // 14. softmax stats over a
  areduce<<<1, 1024, 0, stream>>>(ascr, stats);
  // 15. pooled partials
  pooled_partial<<<dim3(8, 32), 256, 0, stream>>>(B2, ascr, stats, part);
  // 16. LN + fc + softmax -> out
  final_kernel<<<1, 512, 0, stream>>>(part, stats, ln_g, ln_b, fc_w, fc_b, out);
}

// Round 4
// 690.109 us; speedup vs baseline: 13.8962x; 2.5546x over previous
//
#include <hip/hip_runtime.h>
#include <math.h>

#define NROWS 16384
#define DIN   384
#define DIM   512
#define KSEL  6
#define NSPLIT 4
#define COLS_PER_SPLIT (NROWS / NSPLIT)   // 4096
#define ATT_SCALE 0.044194173824159216f   // 512^-0.5

typedef unsigned short u16;
typedef __attribute__((ext_vector_type(8))) short bf16x8;
typedef __attribute__((ext_vector_type(16))) float f32x16;

static __device__ __forceinline__ float lrelu_f(float v) {
  return v > 0.f ? v : 0.01f * v;
}

static __device__ __forceinline__ u16 f2bf(float f) {  // RNE f32->bf16
  unsigned u = __float_as_uint(f);
  unsigned r = (u + 0x7FFFu + ((u >> 16) & 1u)) >> 16;
  return (u16)r;
}

static __device__ __forceinline__ void sbar() {
  asm volatile("" ::: "memory");
  __builtin_amdgcn_s_barrier();
  asm volatile("" ::: "memory");
}

// ---------------------------------------------------------------------------
// small elementwise kernels
// ---------------------------------------------------------------------------
__global__ __launch_bounds__(256)
void convx(const float* __restrict__ X, u16* __restrict__ Xb) {
  int i = blockIdx.x * 256 + threadIdx.x;           // 8-elem chunk
  const float4* p = (const float4*)X + (size_t)i * 2;
  float4 a = p[0], b = p[1];
  uint4 o;
  o.x = f2bf(a.x) | ((unsigned)f2bf(a.y) << 16);
  o.y = f2bf(a.z) | ((unsigned)f2bf(a.w) << 16);
  o.z = f2bf(b.x) | ((unsigned)f2bf(b.y) << 16);
  o.w = f2bf(b.z) | ((unsigned)f2bf(b.w) << 16);
  ((uint4*)Xb)[i] = o;
}

__global__ __launch_bounds__(256)
void wconv(const float* __restrict__ W, u16* __restrict__ Wt, int K, int N) {
  int t = blockIdx.x * 256 + threadIdx.x;
  if (t >= K * N) return;
  int k = t / N, n = t - k * N;
  Wt[(size_t)n * K + k] = f2bf(W[t]);
}

__global__ __launch_bounds__(256)
void colsum_partial(const float* __restrict__ H, float* __restrict__ part) {
  int col = blockIdx.x * 64 + (threadIdx.x & 63);
  int sub = threadIdx.x >> 6;
  int rEnd = blockIdx.y * 512 + 512;
  float s = 0.f;
  for (int r = blockIdx.y * 512 + sub; r < rEnd; r += 4)
    s += H[(size_t)r * DIM + col];
  __shared__ float sh[4][64];
  sh[sub][threadIdx.x & 63] = s;
  __syncthreads();
  if (threadIdx.x < 64) {
    float tot = sh[0][threadIdx.x] + sh[1][threadIdx.x] +
                sh[2][threadIdx.x] + sh[3][threadIdx.x];
    part[(size_t)blockIdx.y * DIM + col] = tot;
  }
}

__global__ void finalize_mean(const float* __restrict__ part,
                              float* __restrict__ mean) {
  int c = threadIdx.x;
  float s = 0.f;
  for (int j = 0; j < 32; j++) s += part[j * DIM + c];
  mean[c] = s * (1.0f / NROWS);
}

// h = (h0 + mean)*0.5, bf16 output only
__global__ __launch_bounds__(256)
void h_fix_bf(const float* __restrict__ H0, const float* __restrict__ mean,
              u16* __restrict__ Hb) {
  int idx = blockIdx.x * 256 + threadIdx.x;         // 8-elem chunk
  int c = (idx * 8) & (DIM - 1);
  const float4* p = (const float4*)H0 + (size_t)idx * 2;
  float4 a = p[0], b = p[1];
  float4 m0 = *(const float4*)(mean + c);
  float4 m1 = *(const float4*)(mean + c + 4);
  a.x = (a.x + m0.x) * 0.5f; a.y = (a.y + m0.y) * 0.5f;
  a.z = (a.z + m0.z) * 0.5f; a.w = (a.w + m0.w) * 0.5f;
  b.x = (b.x + m1.x) * 0.5f; b.y = (b.y + m1.y) * 0.5f;
  b.z = (b.z + m1.z) * 0.5f; b.w = (b.w + m1.w) * 0.5f;
  uint4 o;
  o.x = f2bf(a.x) | ((unsigned)f2bf(a.y) << 16);
  o.y = f2bf(a.z) | ((unsigned)f2bf(a.w) << 16);
  o.z = f2bf(b.x) | ((unsigned)f2bf(b.y) << 16);
  o.w = f2bf(b.z) | ((unsigned)f2bf(b.w) << 16);
  ((uint4*)Hb)[idx] = o;
}

// ---------------------------------------------------------------------------
// bf16 MFMA GEMM: C[M=16384, N] = act(A[M,K]bf16 @ Wt[N,K]^T + bias), opt +=,
// opt bf16 dual-store (scaled). Tile 128x128, BK=64, 4 waves (2x2), each wave
// 2 mfrag x 2 nfrag of 32x32x16. A/W via global_load_lds (source-permuted XOR
// swizzle, linear LDS dest), double-buffered, single-barrier pipeline.
// ---------------------------------------------------------------------------
template<int ACT, int ACCUM, int STOREBF>
__global__ __launch_bounds__(256, 2)
void gemm_bf16(const u16* __restrict__ A, const u16* __restrict__ Wt,
               const float* __restrict__ bias, float* __restrict__ C,
               u16* __restrict__ Cb, float bscale, int K, int N) {
  __shared__ char lds[65536];   // A dbuf [0,32K), W dbuf [32K,64K)
  const int tid = threadIdx.x;
  const int w = tid >> 6, l = tid & 63;
  const int l31 = l & 31, lh = l >> 5, lh16 = lh << 4;
  const int qg = w & 1, ng = w >> 1;
  const int swz = (l31 & 7) << 4;
  const int rowBase = blockIdx.y * 128;
  const int colBase = blockIdx.x * 128;
  const int nsteps = K >> 6;

  f32x16 z;
  #pragma unroll
  for (int i = 0; i < 16; i++) z[i] = 0.f;
  f32x16 acc00 = z, acc01 = z, acc10 = z, acc11 = z;

#define GSTAGE(buf_, kc_) do { \
    const int r_ = tid >> 3, j_ = tid & 7; \
    const int js_ = ((j_ ^ (r_ & 7)) << 3); \
    const u16* as_ = A + (size_t)rowBase * K + (kc_); \
    const u16* ws_ = Wt + (size_t)colBase * K + (kc_); \
    char* ab_ = lds + (buf_) * 16384; \
    char* wb_ = lds + 32768 + (buf_) * 16384; \
    _Pragma("unroll") \
    for (int p_ = 0; p_ < 4; ++p_) { \
      __builtin_amdgcn_global_load_lds( \
        (const __attribute__((address_space(1))) void*)(as_ + (size_t)(r_ + 32 * p_) * K + js_), \
        (__attribute__((address_space(3))) void*)(ab_ + w * 1024 + p_ * 4096), 16, 0, 0); \
      __builtin_amdgcn_global_load_lds( \
        (const __attribute__((address_space(1))) void*)(ws_ + (size_t)(r_ + 32 * p_) * K + js_), \
        (__attribute__((address_space(3))) void*)(wb_ + w * 1024 + p_ * 4096), 16, 0, 0); \
    } \
  } while (0)

  GSTAGE(0, 0);
  asm volatile("s_waitcnt vmcnt(0)" ::: "memory");
  sbar();
  #pragma unroll 1
  for (int s = 0; s < nsteps; ++s) {
    const int cur = s & 1;
    if (s + 1 < nsteps) GSTAGE(cur ^ 1, (s + 1) * 64);
    __builtin_amdgcn_sched_barrier(0);
    const char* ab = lds + cur * 16384;
    const char* wb = lds + 32768 + cur * 16384;
    #pragma unroll
    for (int s4 = 0; s4 < 4; ++s4) {
      const int off = (s4 * 32 + lh16) ^ swz;
      bf16x8 am0 = *(const bf16x8*)(ab + (qg * 64 + l31) * 128 + off);
      bf16x8 am1 = *(const bf16x8*)(ab + (qg * 64 + 32 + l31) * 128 + off);
      bf16x8 wn0 = *(const bf16x8*)(wb + (ng * 64 + l31) * 128 + off);
      bf16x8 wn1 = *(const bf16x8*)(wb + (ng * 64 + 32 + l31) * 128 + off);
      acc00 = __builtin_amdgcn_mfma_f32_32x32x16_bf16(wn0, am0, acc00, 0, 0, 0);
      acc01 = __builtin_amdgcn_mfma_f32_32x32x16_bf16(wn1, am0, acc01, 0, 0, 0);
      acc10 = __builtin_amdgcn_mfma_f32_32x32x16_bf16(wn0, am1, acc10, 0, 0, 0);
      acc11 = __builtin_amdgcn_mfma_f32_32x32x16_bf16(wn1, am1, acc11, 0, 0, 0);
    }
    asm volatile("s_waitcnt vmcnt(0)" ::: "memory");
    sbar();
  }
#undef GSTAGE

  // epilogue: spill to LDS (XOR-swizzled cols), then coalesced store
  float* Ls = (float*)lds;
  {
    const int m0 = qg * 64 + l31;
    const int k0 = (m0 & 7) << 2;
    #pragma unroll
    for (int r = 0; r < 16; ++r) {
      const int nd = ng * 64 + (r & 3) + 8 * (r >> 2) + 4 * lh;
      Ls[m0 * 128 + (nd ^ k0)] = acc00[r];
      Ls[m0 * 128 + ((nd + 32) ^ k0)] = acc01[r];
      Ls[(m0 + 32) * 128 + (nd ^ k0)] = acc10[r];
      Ls[(m0 + 32) * 128 + ((nd + 32) ^ k0)] = acc11[r];
    }
  }
  sbar();
  #pragma unroll
  for (int p = 0; p < 16; ++p) {
    int idx = tid + 256 * p;
    int m = idx >> 5, c4 = (idx & 31) << 2;
    float4 v = *(const float4*)&Ls[m * 128 + (c4 ^ ((m & 7) << 2))];
    int col = colBase + c4;
    float4 bv = *(const float4*)&bias[col];
    v.x += bv.x; v.y += bv.y; v.z += bv.z; v.w += bv.w;
    if (ACT) {
      v.x = lrelu_f(v.x); v.y = lrelu_f(v.y);
      v.z = lrelu_f(v.z); v.w = lrelu_f(v.w);
    }
    size_t o = (size_t)(rowBase + m) * N + col;
    if (ACCUM) {
      float4 c0 = *(const float4*)&C[o];
      v.x += c0.x; v.y += c0.y; v.z += c0.z; v.w += c0.w;
    }
    *(float4*)&C[o] = v;
    if (STOREBF) {
      ushort4 q;
      q.x = f2bf(v.x * bscale); q.y = f2bf(v.y * bscale);
      q.z = f2bf(v.z * bscale); q.w = f2bf(v.w * bscale);
      *(ushort4*)&Cb[o] = q;
    }
  }
}

// ---------------------------------------------------------------------------
// MFMA attn-logit + per-row top-6. 512 blocks: split=bid&3 (XCD-affine),
// rowTile=bid>>2. Tile 128q x 128n, BK=64, 4 waves (qg,ng in 2x2), each wave
// 2 qfrag x 2 nfrag 32x32x16, swapped operands mfma(neighbor, query, acc):
// lane&31 = query row -> in-register top-6, no score spill. A/B dbuf via
// global_load_lds + source-permuted XOR swizzle; single-barrier pipeline.
// ---------------------------------------------------------------------------
#define T6(tv, tix, vv, cc) do { float v_ = (vv); \
  if (v_ > tv[5]) { tv[5] = v_; tix[5] = (cc); \
    if (tv[5] > tv[4]) { float t=tv[4];tv[4]=tv[5];tv[5]=t; int q=tix[4];tix[4]=tix[5];tix[5]=q; } \
    if (tv[4] > tv[3]) { float t=tv[3];tv[3]=tv[4];tv[4]=t; int q=tix[3];tix[3]=tix[4];tix[4]=q; } \
    if (tv[3] > tv[2]) { float t=tv[2];tv[2]=tv[3];tv[3]=t; int q=tix[2];tix[2]=tix[3];tix[3]=q; } \
    if (tv[2] > tv[1]) { float t=tv[1];tv[1]=tv[2];tv[2]=t; int q=tix[1];tix[1]=tix[2];tix[2]=q; } \
    if (tv[1] > tv[0]) { float t=tv[0];tv[0]=tv[1];tv[1]=t; int q=tix[0];tix[0]=tix[1];tix[1]=q; } \
  } } while (0)

__global__ __launch_bounds__(256, 2)
void attn_topk_mfma(const u16* __restrict__ EHb, const u16* __restrict__ ETb,
                    float* __restrict__ TWp, int* __restrict__ TIp) {
  __shared__ char lds[65536];   // A dbuf [0,32K), B dbuf [32K,64K)
  const int tid = threadIdx.x;
  const int w = tid >> 6, l = tid & 63;
  const int l31 = l & 31, lh = l >> 5, lh16 = lh << 4;
  const int qg = w & 1, ng = w >> 1;
  const int swz = (l31 & 7) << 4;

  const int bid = blockIdx.x;
  const int split = bid & 3;
  const int rowBase = (bid >> 2) * 128;

  f32x16 z;
  #pragma unroll
  for (int i = 0; i < 16; i++) z[i] = 0.f;
  f32x16 acc00 = z, acc01 = z, acc10 = z, acc11 = z;

  float tvA[KSEL], tvB[KSEL]; int tixA[KSEL], tixB[KSEL];
  #pragma unroll
  for (int k = 0; k < KSEL; k++) {
    tvA[k] = -INFINITY; tixA[k] = 0; tvB[k] = -INFINITY; tixB[k] = 0;
  }

#define STAGE_AB(buf_, nct_, nkc_) do { \
    const int r_ = tid >> 3, j_ = tid & 7; \
    const int js_ = ((j_ ^ (r_ & 7)) << 3); \
    const u16* as_ = EHb + (size_t)rowBase * DIM + (nkc_) * 64; \
    const u16* bs_ = ETb + (size_t)(split * COLS_PER_SPLIT + (nct_) * 128) * DIM + (nkc_) * 64; \
    char* ab_ = lds + (buf_) * 16384; \
    char* bb_ = lds + 32768 + (buf_) * 16384; \
    _Pragma("unroll") \
    for (int p_ = 0; p_ < 4; ++p_) { \
      __builtin_amdgcn_global_load_lds( \
        (const __attribute__((address_space(1))) void*)(as_ + (size_t)(r_ + 32 * p_) * DIM + js_), \
        (__attribute__((address_space(3))) void*)(ab_ + w * 1024 + p_ * 4096), 16, 0, 0); \
      __builtin_amdgcn_global_load_lds( \
        (const __attribute__((address_space(1))) void*)(bs_ + (size_t)(r_ + 32 * p_) * DIM + js_), \
        (__attribute__((address_space(3))) void*)(bb_ + w * 1024 + p_ * 4096), 16, 0, 0); \
    } \
  } while (0)

  STAGE_AB(0, 0, 0);
  asm volatile("s_waitcnt vmcnt(0)" ::: "memory");
  sbar();
  #pragma unroll 1
  for (int s = 0; s < 256; ++s) {            // 32 ct x 8 kc
    const int cur = s & 1;
    if (s + 1 < 256) {
      const int ns = s + 1;
      STAGE_AB(cur ^ 1, ns >> 3, ns & 7);
    }
    __builtin_amdgcn_sched_barrier(0);
    const char* ab = lds + cur * 16384;
    const char* bb = lds + 32768 + cur * 16384;
    #pragma unroll
    for (int s4 = 0; s4 < 4; ++s4) {
      const int off = (s4 * 32 + lh16) ^ swz;
      bf16x8 aq0 = *(const bf16x8*)(ab + (qg * 64 + l31) * 128 + off);
      bf16x8 aq1 = *(const bf16x8*)(ab + (qg * 64 + 32 + l31) * 128 + off);
      bf16x8 bn0 = *(const bf16x8*)(bb + (ng * 64 + l31) * 128 + off);
      bf16x8 bn1 = *(const bf16x8*)(bb + (ng * 64 + 32 + l31) * 128 + off);
      acc00 = __builtin_amdgcn_mfma_f32_32x32x16_bf16(bn0, aq0, acc00, 0, 0, 0);
      acc01 = __builtin_amdgcn_mfma_f32_32x32x16_bf16(bn1, aq0, acc01, 0, 0, 0);
      acc10 = __builtin_amdgcn_mfma_f32_32x32x16_bf16(bn0, aq1, acc10, 0, 0, 0);
      acc11 = __builtin_amdgcn_mfma_f32_32x32x16_bf16(bn1, aq1, acc11, 0, 0, 0);
    }
    if ((s & 7) == 7) {                      // end of K for tile ct = s>>3
      const int cb = split * COLS_PER_SPLIT + (s >> 3) * 128 + ng * 64 + 4 * lh;
      #pragma unroll
      for (int r = 0; r < 16; ++r) {
        const int nd = cb + (r & 3) + 8 * (r >> 2);
        T6(tvA, tixA, acc00[r], nd);
        T6(tvB, tixB, acc10[r], nd);
      }
      #pragma unroll
      for (int r = 0; r < 16; ++r) {
        const int nd = cb + 32 + (r & 3) + 8 * (r >> 2);
        T6(tvA, tixA, acc01[r], nd);
        T6(tvB, tixB, acc11[r], nd);
      }
      acc00 = z; acc01 = z; acc10 = z; acc11 = z;
    }
    asm volatile("s_waitcnt vmcnt(0)" ::: "memory");
    sbar();
  }
#undef STAGE_AB

  // merge 4 partial lists per query row (ng x lh)
  float* MV = (float*)lds;
  int* MI = (int*)(lds + 12288);
  {
    const int src = ng * 2 + lh;
    const int q0 = qg * 64 + l31;
    #pragma unroll
    for (int k = 0; k < KSEL; k++) {
      MV[(q0 * 4 + src) * 6 + k] = tvA[k];
      MI[(q0 * 4 + src) * 6 + k] = tixA[k];
      MV[((q0 + 32) * 4 + src) * 6 + k] = tvB[k];
      MI[((q0 + 32) * 4 + src) * 6 + k] = tixB[k];
    }
  }
  sbar();
  if (tid < 128) {
    int mb = tid * 24;
    unsigned used = 0;
    float ov[KSEL]; int oi[KSEL];
    #pragma unroll
    for (int s = 0; s < KSEL; ++s) {
      float bvv = -INFINITY; int bi = 0x7fffffff; int be = 0;
      for (int e = 0; e < 24; ++e) {
        if (used & (1u << e)) continue;
        float v = MV[mb + e]; int ix = MI[mb + e];
        if (v > bvv || (v == bvv && ix < bi)) { bvv = v; bi = ix; be = e; }
      }
      used |= 1u << be;
      ov[s] = bvv; oi[s] = bi;
    }
    size_t o = ((size_t)split * NROWS + rowBase + tid) * KSEL;
    #pragma unroll
    for (int k = 0; k < KSEL; k++) { TWp[o + k] = ov[k]; TIp[o + k] = oi[k]; }
  }
}

// Merge NSPLIT per-split top-6 lists into global top-6 (value desc, idx asc).
__global__ __launch_bounds__(256)
void topk_merge(const float* __restrict__ TWp, const int* __restrict__ TIp,
                float* __restrict__ TW, int* __restrict__ TI) {
  int row = blockIdx.x * 256 + threadIdx.x;
  float tv[KSEL]; int tix[KSEL];
  #pragma unroll
  for (int k = 0; k < KSEL; k++) { tv[k] = -INFINITY; tix[k] = 0x7fffffff; }
  #pragma unroll
  for (int s = 0; s < NSPLIT; s++) {
    size_t o = ((size_t)s * NROWS + row) * KSEL;
    #pragma unroll
    for (int k = 0; k < KSEL; k++) {
      float cv = TWp[o + k]; int ci = TIp[o + k];
      bool better5 = (cv > tv[5]) || (cv == tv[5] && ci < tix[5]);
      if (better5) {
        tv[5] = cv; tix[5] = ci;
        if ((tv[5] > tv[4]) || (tv[5] == tv[4] && tix[5] < tix[4])) {
          float t = tv[4]; tv[4] = tv[5]; tv[5] = t;
          int ti = tix[4]; tix[4] = tix[5]; tix[5] = ti; }
        if ((tv[4] > tv[3]) || (tv[4] == tv[3] && tix[4] < tix[3])) {
          float t = tv[3]; tv[3] = tv[4]; tv[4] = t;
          int ti = tix[3]; tix[3] = tix[4]; tix[4] = ti; }
        if ((tv[3] > tv[2]) || (tv[3] == tv[2] && tix[3] < tix[2])) {
          float t = tv[2]; tv[2] = tv[3]; tv[3] = t;
          int ti = tix[2]; tix[2] = tix[3]; tix[3] = ti; }
        if ((tv[2] > tv[1]) || (tv[2] == tv[1] && tix[2] < tix[1])) {
          float t = tv[1]; tv[1] = tv[2]; tv[2] = t;
          int ti = tix[1]; tix[1] = tix[2]; tix[2] = ti; }
        if ((tv[1] > tv[0]) || (tv[1] == tv[0] && tix[1] < tix[0])) {
          float t = tv[0]; tv[0] = tv[1]; tv[1] = t;
          int ti = tix[0]; tix[0] = tix[1]; tix[1] = ti; }
      }
    }
  }
  size_t o = (size_t)row * KSEL;
  #pragma unroll
  for (int k = 0; k < KSEL; k++) { TW[o + k] = tv[k]; TI[o + k] = tix[k]; }
}

// ---------------------------------------------------------------------------
// Neighbor aggregation. One wave per row; writes bf16 s_in / b_in.
// ---------------------------------------------------------------------------
__global__ __launch_bounds__(256)
void neighbor_kernel(const float* __restrict__ EH, const float* __restrict__ ET,
                     const float* __restrict__ TW, const int* __restrict__ TI,
                     u16* __restrict__ SINb, u16* __restrict__ BINb) {
  const int lane = threadIdx.x & 63;
  const int row = blockIdx.x * 4 + (threadIdx.x >> 6);
  const float* eh = EH + (size_t)row * DIM;
  float ehv[8];
  #pragma unroll
  for (int u = 0; u < 8; u++) ehv[u] = eh[u * 64 + lane];
  float tw[KSEL]; int ti[KSEL];
  #pragma unroll
  for (int k = 0; k < KSEL; k++) {
    tw[k] = TW[(size_t)row * KSEL + k];
    ti[k] = TI[(size_t)row * KSEL + k];
  }
  float m = tw[0];
  #pragma unroll
  for (int k = 1; k < KSEL; k++) m = fmaxf(m, tw[k]);
  float p[KSEL], ps = 0.f;
  #pragma unroll
  for (int k = 0; k < KSEL; k++) { p[k] = expf(tw[k] - m); ps += p[k]; }
  float inv = 1.f / ps;
  #pragma unroll
  for (int k = 0; k < KSEL; k++) p[k] *= inv;

  float nb[KSEL][8];
  float kaw[KSEL];
  #pragma unroll
  for (int k = 0; k < KSEL; k++) {
    const float* et = ET + (size_t)ti[k] * DIM;
    float snb = 0.f, sg = 0.f;
    #pragma unroll
    for (int u = 0; u < 8; u++) {
      float nbv = et[u * 64 + lane];
      nb[k][u] = nbv;
      float ehr = p[k] * nbv + (1.f - p[k]) * ehv[u];
      float g = tanhf(ehv[u] + ehr);
      snb += nbv; sg += g;
    }
    #pragma unroll
    for (int off = 32; off > 0; off >>= 1) {
      snb += __shfl_xor(snb, off);
      sg  += __shfl_xor(sg, off);
    }
    kaw[k] = snb * sg;
  }
  float km = kaw[0];
  #pragma unroll
  for (int k = 1; k < KSEL; k++) km = fmaxf(km, kaw[k]);
  float kp[KSEL], ks = 0.f;
  #pragma unroll
  for (int k = 0; k < KSEL; k++) { kp[k] = expf(kaw[k] - km); ks += kp[k]; }
  float kinv = 1.f / ks;
  #pragma unroll
  for (int k = 0; k < KSEL; k++) kp[k] *= kinv;

  #pragma unroll
  for (int u = 0; u < 8; u++) {
    float enh = 0.f;
    #pragma unroll
    for (int k = 0; k < KSEL; k++) enh += kp[k] * nb[k][u];
    size_t o = (size_t)row * DIM + u * 64 + lane;
    SINb[o] = f2bf(ehv[u] + enh);
    BINb[o] = f2bf(ehv[u] * enh);
  }
}

__global__ __launch_bounds__(256)
void att2_kernel(const float* __restrict__ HID, const float* __restrict__ w2,
                 const float* __restrict__ b2, float* __restrict__ ASC) {
  const int lane = threadIdx.x & 63;
  const int row = blockIdx.x * 4 + (threadIdx.x >> 6);
  float4 hv = ((const float4*)(HID + (size_t)row * 256))[lane];
  float4 wv = ((const float4*)w2)[lane];
  float s = hv.x * wv.x + hv.y * wv.y + hv.z * wv.z + hv.w * wv.w;
  #pragma unroll
  for (int off = 32; off > 0; off >>= 1) s += __shfl_xor(s, off);
  if (lane == 0) ASC[row] = s + b2[0];
}

__global__ __launch_bounds__(1024)
void areduce(const float* __restrict__ ASC, float* __restrict__ stats) {
  __shared__ float sm[1024];
  int t = threadIdx.x;
  float m = -INFINITY;
  for (int i = t; i < NROWS; i += 1024) m = fmaxf(m, ASC[i]);
  sm[t] = m; __syncthreads();
  for (int s = 512; s > 0; s >>= 1) {
    if (t < s) sm[t] = fmaxf(sm[t], sm[t + s]);
    __syncthreads();
  }
  float mx = sm[0]; __syncthreads();
  float sum = 0.f;
  for (int i = t; i < NROWS; i += 1024) sum += expf(ASC[i] - mx);
  sm[t] = sum; __syncthreads();
  for (int s = 512; s > 0; s >>= 1) {
    if (t < s) sm[t] += sm[t + s];
    __syncthreads();
  }
  if (t == 0) { stats[0] = mx; stats[1] = sm[0]; }
}

__global__ __launch_bounds__(256)
void pooled_partial(const float* __restrict__ EMB, const float* __restrict__ ASC,
                    const float* __restrict__ stats, float* __restrict__ part) {
  int col = blockIdx.x * 64 + (threadIdx.x & 63);
  int sub = threadIdx.x >> 6;
  float mx = stats[0];
  int rEnd = blockIdx.y * 512 + 512;
  float s = 0.f;
  for (int r = blockIdx.y * 512 + sub; r < rEnd; r += 4)
    s += expf(ASC[r] - mx) * EMB[(size_t)r * DIM + col];
  __shared__ float sh[4][64];
  sh[sub][threadIdx.x & 63] = s;
  __syncthreads();
  if (threadIdx.x < 64) {
    float tot = sh[0][threadIdx.x] + sh[1][threadIdx.x] +
                sh[2][threadIdx.x] + sh[3][threadIdx.x];
    part[(size_t)blockIdx.y * DIM + col] = tot;
  }
}

__global__ __launch_bounds__(512)
void final_kernel(const float* __restrict__ part, const float* __restrict__ stats,
                  const float* __restrict__ ln_g, const float* __restrict__ ln_b,
                  const float* __restrict__ fc_w, const float* __restrict__ fc_b,
                  float* __restrict__ out) {
  __shared__ float sh[512];
  int t = threadIdx.x;
  float s = 0.f;
  for (int j = 0; j < 32; j++) s += part[j * DIM + t];
  float pooled = s / stats[1];
  sh[t] = pooled; __syncthreads();
  for (int off = 256; off > 0; off >>= 1) {
    if (t < off) sh[t] += sh[t + off];
    __syncthreads();
  }
  float mu = sh[0] * (1.f / DIM); __syncthreads();
  float dv = pooled - mu;
  sh[t] = dv * dv; __syncthreads();
  for (int off = 256; off > 0; off >>= 1) {
    if (t < off) sh[t] += sh[t + off];
    __syncthreads();
  }
  float var = sh[0] * (1.f / DIM); __syncthreads();
  float normed = dv * rsqrtf(var + 1e-5f) * ln_g[t] + ln_b[t];
  sh[t] = normed * fc_w[t * 2 + 0]; __syncthreads();
  for (int off = 256; off > 0; off >>= 1) {
    if (t < off) sh[t] += sh[t + off];
    __syncthreads();
  }
  float l0 = sh[0] + fc_b[0]; __syncthreads();
  sh[t] = normed * fc_w[t * 2 + 1]; __syncthreads();
  for (int off = 256; off > 0; off >>= 1) {
    if (t < off) sh[t] += sh[t + off];
    __syncthreads();
  }
  float l1 = sh[0] + fc_b[1];
  if (t == 0) {
    float mm = fmaxf(l0, l1);
    float e0 = expf(l0 - mm), e1 = expf(l1 - mm);
    float si = 1.f / (e0 + e1);
    out[0] = l0; out[1] = l1; out[2] = e0 * si; out[3] = e1 * si;
  }
}

// ---------------------------------------------------------------------------
extern "C" void kernel_launch(void* const* d_in, const int* in_sizes, int n_in,
                              void* d_out, int out_size, void* d_ws, size_t ws_size,
                              hipStream_t stream) {
  (void)in_sizes; (void)n_in; (void)out_size; (void)ws_size;
  const float* x      = (const float*)d_in[0];
  const float* fc1_w  = (const float*)d_in[1];
  const float* fc1_b  = (const float*)d_in[2];
  const float* wh_w   = (const float*)d_in[3];
  const float* wh_b   = (const float*)d_in[4];
  const float* wt_w   = (const float*)d_in[5];
  const float* wt_b   = (const float*)d_in[6];
  const float* lin1_w = (const float*)d_in[7];
  const float* lin1_b = (const float*)d_in[8];
  const float* lin2_w = (const float*)d_in[9];
  const float* lin2_b = (const float*)d_in[10];
  const float* att1_w = (const float*)d_in[11];
  const float* att1_b = (const float*)d_in[12];
  const float* att2_w = (const float*)d_in[13];
  const float* att2_b = (const float*)d_in[14];
  const float* ln_g   = (const float*)d_in[15];
  const float* ln_b   = (const float*)d_in[16];
  const float* fc_w   = (const float*)d_in[17];
  const float* fc_b   = (const float*)d_in[18];
  float* out = (float*)d_out;

  char* ws = (char*)d_ws;
  float* B0   = (float*)(ws);                       // h0 -> HID
  float* B1   = (float*)(ws + 33554432);            // [xb] -> e_h
  float* B2   = (float*)(ws + 67108864);            // e_t -> emb
  float* TWp  = (float*)(ws + 100663296);
  int*   TIp  = (int*)  (ws + 100663296 + 1572864);
  float* TW   = (float*)(ws + 100663296 + 3145728);
  int*   TI   = (int*)  (ws + 100663296 + 3145728 + 393216);
  float* part = (float*)(ws + 100663296 + 3145728 + 786432);
  float* mean = (float*)(ws + 100663296 + 3145728 + 786432 + 65536);
  float* ascr = (float*)(ws + 100663296 + 3145728 + 786432 + 65536 + 2048);
  float* stats= (float*)(ws + 100663296 + 3145728 + 786432 + 65536 + 2048 + 65536);
  u16*   hb   = (u16*)(ws + 104732672);             // -> embb
  u16*   EHb  = (u16*)(ws + 104732672 + 16777216);  // -> sinb
  u16*   ETb  = (u16*)(ws + 104732672 + 33554432);  // -> binb
  u16*   WT   = (u16*)(ws + 104732672 + 50331648);  // transposed bf16 weights
  u16* fc1t = WT;
  u16* wht  = fc1t + 196608;
  u16* wtt  = wht + 262144;
  u16* lin1t= wtt + 262144;
  u16* lin2t= lin1t + 262144;
  u16* att1t= lin2t + 262144;
  u16* xb   = (u16*)B1;      // temp in B1 region, dead before e_h written
  u16* sinb = EHb;           // reuse after attn
  u16* binb = ETb;
  u16* embb = hb;

  // 0. input + weight conversions (bf16, weights transposed to [N][K])
  convx<<<3072, 256, 0, stream>>>(x, xb);
  wconv<<<768, 256, 0, stream>>>(fc1_w, fc1t, 384, 512);
  wconv<<<1024, 256, 0, stream>>>(wh_w, wht, 512, 512);
  wconv<<<1024, 256, 0, stream>>>(wt_w, wtt, 512, 512);
  wconv<<<1024, 256, 0, stream>>>(lin1_w, lin1t, 512, 512);
  wconv<<<1024, 256, 0, stream>>>(lin2_w, lin2t, 512, 512);
  wconv<<<512, 256, 0, stream>>>(att1_w, att1t, 512, 256);
  // 1. h0 = lrelu(x @ fc1_w + b)
  gemm_bf16<1,0,0><<<dim3(4,128), 256, 0, stream>>>(xb, fc1t, fc1_b, B0, nullptr, 1.f, 384, 512);
  // 2-4. column mean; hb = bf16((h0+mean)*0.5)
  colsum_partial<<<dim3(8,32), 256, 0, stream>>>(B0, part);
  finalize_mean<<<1, 512, 0, stream>>>(part, mean);
  h_fix_bf<<<4096, 256, 0, stream>>>(B0, mean, hb);
  // 5-6. e_h (f32 + bf16*SCALE), e_t (f32 + bf16)
  gemm_bf16<0,0,1><<<dim3(4,128), 256, 0, stream>>>(hb, wht, wh_b, B1, EHb, ATT_SCALE, 512, 512);
  gemm_bf16<0,0,1><<<dim3(4,128), 256, 0, stream>>>(hb, wtt, wt_b, B2, ETb, 1.f, 512, 512);
  // 7. fused MFMA attn-logit + top-6 per split, then merge
  attn_topk_mfma<<<512, 256, 0, stream>>>(EHb, ETb, TWp, TIp);
  topk_merge<<<64, 256, 0, stream>>>(TWp, TIp, TW, TI);
  // 8. neighbor aggregation -> bf16 s_in / b_in
  neighbor_kernel<<<4096, 256, 0, stream>>>(B1, B2, TW, TI, sinb, binb);
  // 9-10. emb = lrelu(s_in@lin1+b) + lrelu(b_in@lin2+b)  (f32 in B2 + bf16)
  gemm_bf16<1,0,0><<<dim3(4,128), 256, 0, stream>>>(sinb, lin1t, lin1_b, B2, nullptr, 1.f, 512, 512);
  gemm_bf16<1,1,1><<<dim3(4,128), 256, 0, stream>>>(binb, lin2t, lin2_b, B2, embb, 1.f, 512, 512);
  // 11. hidden = lrelu(emb@att1+b) -> B0 f32
  gemm_bf16<1,0,0><<<dim3(2,128), 256, 0, stream>>>(embb, att1t, att1_b, B0, nullptr, 1.f, 512, 256);
  // 12-15. readout
  att2_kernel<<<4096, 256, 0, stream>>>(B0, att2_w, att2_b, ascr);
  areduce<<<1, 1024, 0, stream>>>(ascr, stats);
  pooled_partial<<<dim3(8,32), 256, 0, stream>>>(B2, ascr, stats, part);
  final_kernel<<<1, 512, 0, stream>>>(part, stats, ln_g, ln_b, fc_w, fc_b, out);
}

// Round 5
// 681.634 us; speedup vs baseline: 14.0690x; 1.0124x over previous
//
#include <hip/hip_runtime.h>
#include <math.h>

#define NROWS 16384
#define DIN   384
#define DIM   512
#define KSEL  6
#define NSPLIT 4
#define COLS_PER_SPLIT (NROWS / NSPLIT)   // 4096
#define ATT_SCALE 0.044194173824159216f   // 512^-0.5

typedef unsigned short u16;
typedef __attribute__((ext_vector_type(8))) short bf16x8;
typedef __attribute__((ext_vector_type(16))) float f32x16;

static __device__ __forceinline__ float lrelu_f(float v) {
  return v > 0.f ? v : 0.01f * v;
}

static __device__ __forceinline__ u16 f2bf(float f) {  // RNE f32->bf16
  unsigned u = __float_as_uint(f);
  unsigned r = (u + 0x7FFFu + ((u >> 16) & 1u)) >> 16;
  return (u16)r;
}

static __device__ __forceinline__ void sbar() {
  asm volatile("" ::: "memory");
  __builtin_amdgcn_s_barrier();
  asm volatile("" ::: "memory");
}

// ---------------------------------------------------------------------------
// small elementwise kernels
// ---------------------------------------------------------------------------
__global__ __launch_bounds__(256)
void convx(const float* __restrict__ X, u16* __restrict__ Xb) {
  int i = blockIdx.x * 256 + threadIdx.x;           // 8-elem chunk
  const float4* p = (const float4*)X + (size_t)i * 2;
  float4 a = p[0], b = p[1];
  uint4 o;
  o.x = f2bf(a.x) | ((unsigned)f2bf(a.y) << 16);
  o.y = f2bf(a.z) | ((unsigned)f2bf(a.w) << 16);
  o.z = f2bf(b.x) | ((unsigned)f2bf(b.y) << 16);
  o.w = f2bf(b.z) | ((unsigned)f2bf(b.w) << 16);
  ((uint4*)Xb)[i] = o;
}

__global__ __launch_bounds__(256)
void wconv(const float* __restrict__ W, u16* __restrict__ Wt, int K, int N) {
  int t = blockIdx.x * 256 + threadIdx.x;
  if (t >= K * N) return;
  int k = t / N, n = t - k * N;
  Wt[(size_t)n * K + k] = f2bf(W[t]);
}

__global__ __launch_bounds__(256)
void colsum_partial(const float* __restrict__ H, float* __restrict__ part) {
  int col = blockIdx.x * 64 + (threadIdx.x & 63);
  int sub = threadIdx.x >> 6;
  int rEnd = blockIdx.y * 512 + 512;
  float s = 0.f;
  for (int r = blockIdx.y * 512 + sub; r < rEnd; r += 4)
    s += H[(size_t)r * DIM + col];
  __shared__ float sh[4][64];
  sh[sub][threadIdx.x & 63] = s;
  __syncthreads();
  if (threadIdx.x < 64) {
    float tot = sh[0][threadIdx.x] + sh[1][threadIdx.x] +
                sh[2][threadIdx.x] + sh[3][threadIdx.x];
    part[(size_t)blockIdx.y * DIM + col] = tot;
  }
}

__global__ void finalize_mean(const float* __restrict__ part,
                              float* __restrict__ mean) {
  int c = threadIdx.x;
  float s = 0.f;
  for (int j = 0; j < 32; j++) s += part[j * DIM + c];
  mean[c] = s * (1.0f / NROWS);
}

// h = (h0 + mean)*0.5, bf16 output only
__global__ __launch_bounds__(256)
void h_fix_bf(const float* __restrict__ H0, const float* __restrict__ mean,
              u16* __restrict__ Hb) {
  int idx = blockIdx.x * 256 + threadIdx.x;         // 8-elem chunk
  int c = (idx * 8) & (DIM - 1);
  const float4* p = (const float4*)H0 + (size_t)idx * 2;
  float4 a = p[0], b = p[1];
  float4 m0 = *(const float4*)(mean + c);
  float4 m1 = *(const float4*)(mean + c + 4);
  a.x = (a.x + m0.x) * 0.5f; a.y = (a.y + m0.y) * 0.5f;
  a.z = (a.z + m0.z) * 0.5f; a.w = (a.w + m0.w) * 0.5f;
  b.x = (b.x + m1.x) * 0.5f; b.y = (b.y + m1.y) * 0.5f;
  b.z = (b.z + m1.z) * 0.5f; b.w = (b.w + m1.w) * 0.5f;
  uint4 o;
  o.x = f2bf(a.x) | ((unsigned)f2bf(a.y) << 16);
  o.y = f2bf(a.z) | ((unsigned)f2bf(a.w) << 16);
  o.z = f2bf(b.x) | ((unsigned)f2bf(b.y) << 16);
  o.w = f2bf(b.z) | ((unsigned)f2bf(b.w) << 16);
  ((uint4*)Hb)[idx] = o;
}

// ---------------------------------------------------------------------------
// bf16 MFMA GEMM: C[M=16384, N] = act(A[M,K]bf16 @ Wt[N,K]^T + bias), opt +=,
// opt bf16 dual-store (scaled). Tile 128x128, BK=64, 4 waves (2x2), each wave
// 2 mfrag x 2 nfrag of 32x32x16. A/W via global_load_lds (source-permuted XOR
// swizzle, linear LDS dest), double-buffered, single-barrier pipeline.
// ---------------------------------------------------------------------------
template<int ACT, int ACCUM, int STOREBF>
__global__ __launch_bounds__(256, 2)
void gemm_bf16(const u16* __restrict__ A, const u16* __restrict__ Wt,
               const float* __restrict__ bias, float* __restrict__ C,
               u16* __restrict__ Cb, float bscale, int K, int N) {
  __shared__ char lds[65536];   // A dbuf [0,32K), W dbuf [32K,64K)
  const int tid = threadIdx.x;
  const int w = tid >> 6, l = tid & 63;
  const int l31 = l & 31, lh = l >> 5, lh16 = lh << 4;
  const int qg = w & 1, ng = w >> 1;
  const int swz = (l31 & 7) << 4;
  const int rowBase = blockIdx.y * 128;
  const int colBase = blockIdx.x * 128;
  const int nsteps = K >> 6;

  f32x16 z;
  #pragma unroll
  for (int i = 0; i < 16; i++) z[i] = 0.f;
  f32x16 acc00 = z, acc01 = z, acc10 = z, acc11 = z;

#define GSTAGE(buf_, kc_) do { \
    const int r_ = tid >> 3, j_ = tid & 7; \
    const int js_ = ((j_ ^ (r_ & 7)) << 3); \
    const u16* as_ = A + (size_t)rowBase * K + (kc_); \
    const u16* ws_ = Wt + (size_t)colBase * K + (kc_); \
    char* ab_ = lds + (buf_) * 16384; \
    char* wb_ = lds + 32768 + (buf_) * 16384; \
    _Pragma("unroll") \
    for (int p_ = 0; p_ < 4; ++p_) { \
      __builtin_amdgcn_global_load_lds( \
        (const __attribute__((address_space(1))) void*)(as_ + (size_t)(r_ + 32 * p_) * K + js_), \
        (__attribute__((address_space(3))) void*)(ab_ + w * 1024 + p_ * 4096), 16, 0, 0); \
      __builtin_amdgcn_global_load_lds( \
        (const __attribute__((address_space(1))) void*)(ws_ + (size_t)(r_ + 32 * p_) * K + js_), \
        (__attribute__((address_space(3))) void*)(wb_ + w * 1024 + p_ * 4096), 16, 0, 0); \
    } \
  } while (0)

  GSTAGE(0, 0);
  asm volatile("s_waitcnt vmcnt(0)" ::: "memory");
  sbar();
  #pragma unroll 1
  for (int s = 0; s < nsteps; ++s) {
    const int cur = s & 1;
    if (s + 1 < nsteps) GSTAGE(cur ^ 1, (s + 1) * 64);
    __builtin_amdgcn_sched_barrier(0);
    const char* ab = lds + cur * 16384;
    const char* wb = lds + 32768 + cur * 16384;
    __builtin_amdgcn_s_setprio(1);
    #pragma unroll
    for (int s4 = 0; s4 < 4; ++s4) {
      const int off = (s4 * 32 + lh16) ^ swz;
      bf16x8 am0 = *(const bf16x8*)(ab + (qg * 64 + l31) * 128 + off);
      bf16x8 am1 = *(const bf16x8*)(ab + (qg * 64 + 32 + l31) * 128 + off);
      bf16x8 wn0 = *(const bf16x8*)(wb + (ng * 64 + l31) * 128 + off);
      bf16x8 wn1 = *(const bf16x8*)(wb + (ng * 64 + 32 + l31) * 128 + off);
      acc00 = __builtin_amdgcn_mfma_f32_32x32x16_bf16(wn0, am0, acc00, 0, 0, 0);
      acc01 = __builtin_amdgcn_mfma_f32_32x32x16_bf16(wn1, am0, acc01, 0, 0, 0);
      acc10 = __builtin_amdgcn_mfma_f32_32x32x16_bf16(wn0, am1, acc10, 0, 0, 0);
      acc11 = __builtin_amdgcn_mfma_f32_32x32x16_bf16(wn1, am1, acc11, 0, 0, 0);
    }
    __builtin_amdgcn_s_setprio(0);
    asm volatile("s_waitcnt vmcnt(0)" ::: "memory");
    sbar();
  }
#undef GSTAGE

  // epilogue: spill to LDS (XOR-swizzled cols), then coalesced store
  float* Ls = (float*)lds;
  {
    const int m0 = qg * 64 + l31;
    const int k0 = (m0 & 7) << 2;
    #pragma unroll
    for (int r = 0; r < 16; ++r) {
      const int nd = ng * 64 + (r & 3) + 8 * (r >> 2) + 4 * lh;
      Ls[m0 * 128 + (nd ^ k0)] = acc00[r];
      Ls[m0 * 128 + ((nd + 32) ^ k0)] = acc01[r];
      Ls[(m0 + 32) * 128 + (nd ^ k0)] = acc10[r];
      Ls[(m0 + 32) * 128 + ((nd + 32) ^ k0)] = acc11[r];
    }
  }
  sbar();
  #pragma unroll
  for (int p = 0; p < 16; ++p) {
    int idx = tid + 256 * p;
    int m = idx >> 5, c4 = (idx & 31) << 2;
    float4 v = *(const float4*)&Ls[m * 128 + (c4 ^ ((m & 7) << 2))];
    int col = colBase + c4;
    float4 bv = *(const float4*)&bias[col];
    v.x += bv.x; v.y += bv.y; v.z += bv.z; v.w += bv.w;
    if (ACT) {
      v.x = lrelu_f(v.x); v.y = lrelu_f(v.y);
      v.z = lrelu_f(v.z); v.w = lrelu_f(v.w);
    }
    size_t o = (size_t)(rowBase + m) * N + col;
    if (ACCUM) {
      float4 c0 = *(const float4*)&C[o];
      v.x += c0.x; v.y += c0.y; v.z += c0.z; v.w += c0.w;
    }
    *(float4*)&C[o] = v;
    if (STOREBF) {
      ushort4 q;
      q.x = f2bf(v.x * bscale); q.y = f2bf(v.y * bscale);
      q.z = f2bf(v.z * bscale); q.w = f2bf(v.w * bscale);
      *(ushort4*)&Cb[o] = q;
    }
  }
}

// ---------------------------------------------------------------------------
// MFMA attn-logit + per-row top-6. 512 blocks, XCD-L2-resident remap:
//   xcd = bid&7, local = bid>>3 (0..63)
//   rowTile = xcd*16 + (local>>2)   -> per-XCD A footprint = 16 x 128KB = 2MB
//   split   = local&3               -> all 4 splits stream through each XCD
// A stays L2-resident across its 32 re-stages; B streams (L3-served).
// Tile 128q x 128n, BK=64, 4 waves (qg,ng 2x2), swapped-operand 32x32x16:
// lane&31 = query row -> in-register top-6, no score spill.
// ---------------------------------------------------------------------------
#define T6(tv, tix, vv, cc) do { float v_ = (vv); \
  if (v_ > tv[5]) { tv[5] = v_; tix[5] = (cc); \
    if (tv[5] > tv[4]) { float t=tv[4];tv[4]=tv[5];tv[5]=t; int q=tix[4];tix[4]=tix[5];tix[5]=q; } \
    if (tv[4] > tv[3]) { float t=tv[3];tv[3]=tv[4];tv[4]=t; int q=tix[3];tix[3]=tix[4];tix[4]=q; } \
    if (tv[3] > tv[2]) { float t=tv[2];tv[2]=tv[3];tv[3]=t; int q=tix[2];tix[2]=tix[3];tix[3]=q; } \
    if (tv[2] > tv[1]) { float t=tv[1];tv[1]=tv[2];tv[2]=t; int q=tix[1];tix[1]=tix[2];tix[2]=q; } \
    if (tv[1] > tv[0]) { float t=tv[0];tv[0]=tv[1];tv[1]=t; int q=tix[0];tix[0]=tix[1];tix[1]=q; } \
  } } while (0)

__global__ __launch_bounds__(256, 2)
void attn_topk_mfma(const u16* __restrict__ EHb, const u16* __restrict__ ETb,
                    float* __restrict__ TWp, int* __restrict__ TIp) {
  __shared__ char lds[65536];   // A dbuf [0,32K), B dbuf [32K,64K)
  const int tid = threadIdx.x;
  const int w = tid >> 6, l = tid & 63;
  const int l31 = l & 31, lh = l >> 5, lh16 = lh << 4;
  const int qg = w & 1, ng = w >> 1;
  const int swz = (l31 & 7) << 4;

  const int bid = blockIdx.x;
  const int xcd = bid & 7;
  const int local = bid >> 3;
  const int split = local & 3;
  const int rowBase = (xcd * 16 + (local >> 2)) * 128;

  f32x16 z;
  #pragma unroll
  for (int i = 0; i < 16; i++) z[i] = 0.f;
  f32x16 acc00 = z, acc01 = z, acc10 = z, acc11 = z;

  float tvA[KSEL], tvB[KSEL]; int tixA[KSEL], tixB[KSEL];
  #pragma unroll
  for (int k = 0; k < KSEL; k++) {
    tvA[k] = -INFINITY; tixA[k] = 0; tvB[k] = -INFINITY; tixB[k] = 0;
  }

#define STAGE_AB(buf_, nct_, nkc_) do { \
    const int r_ = tid >> 3, j_ = tid & 7; \
    const int js_ = ((j_ ^ (r_ & 7)) << 3); \
    const u16* as_ = EHb + (size_t)rowBase * DIM + (nkc_) * 64; \
    const u16* bs_ = ETb + (size_t)(split * COLS_PER_SPLIT + (nct_) * 128) * DIM + (nkc_) * 64; \
    char* ab_ = lds + (buf_) * 16384; \
    char* bb_ = lds + 32768 + (buf_) * 16384; \
    _Pragma("unroll") \
    for (int p_ = 0; p_ < 4; ++p_) { \
      __builtin_amdgcn_global_load_lds( \
        (const __attribute__((address_space(1))) void*)(as_ + (size_t)(r_ + 32 * p_) * DIM + js_), \
        (__attribute__((address_space(3))) void*)(ab_ + w * 1024 + p_ * 4096), 16, 0, 0); \
      __builtin_amdgcn_global_load_lds( \
        (const __attribute__((address_space(1))) void*)(bs_ + (size_t)(r_ + 32 * p_) * DIM + js_), \
        (__attribute__((address_space(3))) void*)(bb_ + w * 1024 + p_ * 4096), 16, 0, 0); \
    } \
  } while (0)

  STAGE_AB(0, 0, 0);
  asm volatile("s_waitcnt vmcnt(0)" ::: "memory");
  sbar();
  #pragma unroll 1
  for (int s = 0; s < 256; ++s) {            // 32 ct x 8 kc
    const int cur = s & 1;
    if (s + 1 < 256) {
      const int ns = s + 1;
      STAGE_AB(cur ^ 1, ns >> 3, ns & 7);
    }
    __builtin_amdgcn_sched_barrier(0);
    const char* ab = lds + cur * 16384;
    const char* bb = lds + 32768 + cur * 16384;
    __builtin_amdgcn_s_setprio(1);
    #pragma unroll
    for (int s4 = 0; s4 < 4; ++s4) {
      const int off = (s4 * 32 + lh16) ^ swz;
      bf16x8 aq0 = *(const bf16x8*)(ab + (qg * 64 + l31) * 128 + off);
      bf16x8 aq1 = *(const bf16x8*)(ab + (qg * 64 + 32 + l31) * 128 + off);
      bf16x8 bn0 = *(const bf16x8*)(bb + (ng * 64 + l31) * 128 + off);
      bf16x8 bn1 = *(const bf16x8*)(bb + (ng * 64 + 32 + l31) * 128 + off);
      acc00 = __builtin_amdgcn_mfma_f32_32x32x16_bf16(bn0, aq0, acc00, 0, 0, 0);
      acc01 = __builtin_amdgcn_mfma_f32_32x32x16_bf16(bn1, aq0, acc01, 0, 0, 0);
      acc10 = __builtin_amdgcn_mfma_f32_32x32x16_bf16(bn0, aq1, acc10, 0, 0, 0);
      acc11 = __builtin_amdgcn_mfma_f32_32x32x16_bf16(bn1, aq1, acc11, 0, 0, 0);
    }
    __builtin_amdgcn_s_setprio(0);
    if ((s & 7) == 7) {                      // end of K for tile ct = s>>3
      const int cb = split * COLS_PER_SPLIT + (s >> 3) * 128 + ng * 64 + 4 * lh;
      #pragma unroll
      for (int r = 0; r < 16; ++r) {
        const int nd = cb + (r & 3) + 8 * (r >> 2);
        T6(tvA, tixA, acc00[r], nd);
        T6(tvB, tixB, acc10[r], nd);
      }
      #pragma unroll
      for (int r = 0; r < 16; ++r) {
        const int nd = cb + 32 + (r & 3) + 8 * (r >> 2);
        T6(tvA, tixA, acc01[r], nd);
        T6(tvB, tixB, acc11[r], nd);
      }
      acc00 = z; acc01 = z; acc10 = z; acc11 = z;
    }
    asm volatile("s_waitcnt vmcnt(0)" ::: "memory");
    sbar();
  }
#undef STAGE_AB

  // merge 4 partial lists per query row (ng x lh)
  float* MV = (float*)lds;
  int* MI = (int*)(lds + 12288);
  {
    const int src = ng * 2 + lh;
    const int q0 = qg * 64 + l31;
    #pragma unroll
    for (int k = 0; k < KSEL; k++) {
      MV[(q0 * 4 + src) * 6 + k] = tvA[k];
      MI[(q0 * 4 + src) * 6 + k] = tixA[k];
      MV[((q0 + 32) * 4 + src) * 6 + k] = tvB[k];
      MI[((q0 + 32) * 4 + src) * 6 + k] = tixB[k];
    }
  }
  sbar();
  if (tid < 128) {
    int mb = tid * 24;
    unsigned used = 0;
    float ov[KSEL]; int oi[KSEL];
    #pragma unroll
    for (int s = 0; s < KSEL; ++s) {
      float bvv = -INFINITY; int bi = 0x7fffffff; int be = 0;
      for (int e = 0; e < 24; ++e) {
        if (used & (1u << e)) continue;
        float v = MV[mb + e]; int ix = MI[mb + e];
        if (v > bvv || (v == bvv && ix < bi)) { bvv = v; bi = ix; be = e; }
      }
      used |= 1u << be;
      ov[s] = bvv; oi[s] = bi;
    }
    size_t o = ((size_t)split * NROWS + rowBase + tid) * KSEL;
    #pragma unroll
    for (int k = 0; k < KSEL; k++) { TWp[o + k] = ov[k]; TIp[o + k] = oi[k]; }
  }
}

// Merge NSPLIT per-split top-6 lists into global top-6 (value desc, idx asc).
__global__ __launch_bounds__(256)
void topk_merge(const float* __restrict__ TWp, const int* __restrict__ TIp,
                float* __restrict__ TW, int* __restrict__ TI) {
  int row = blockIdx.x * 256 + threadIdx.x;
  float tv[KSEL]; int tix[KSEL];
  #pragma unroll
  for (int k = 0; k < KSEL; k++) { tv[k] = -INFINITY; tix[k] = 0x7fffffff; }
  #pragma unroll
  for (int s = 0; s < NSPLIT; s++) {
    size_t o = ((size_t)s * NROWS + row) * KSEL;
    #pragma unroll
    for (int k = 0; k < KSEL; k++) {
      float cv = TWp[o + k]; int ci = TIp[o + k];
      bool better5 = (cv > tv[5]) || (cv == tv[5] && ci < tix[5]);
      if (better5) {
        tv[5] = cv; tix[5] = ci;
        if ((tv[5] > tv[4]) || (tv[5] == tv[4] && tix[5] < tix[4])) {
          float t = tv[4]; tv[4] = tv[5]; tv[5] = t;
          int ti = tix[4]; tix[4] = tix[5]; tix[5] = ti; }
        if ((tv[4] > tv[3]) || (tv[4] == tv[3] && tix[4] < tix[3])) {
          float t = tv[3]; tv[3] = tv[4]; tv[4] = t;
          int ti = tix[3]; tix[3] = tix[4]; tix[4] = ti; }
        if ((tv[3] > tv[2]) || (tv[3] == tv[2] && tix[3] < tix[2])) {
          float t = tv[2]; tv[2] = tv[3]; tv[3] = t;
          int ti = tix[2]; tix[2] = tix[3]; tix[3] = ti; }
        if ((tv[2] > tv[1]) || (tv[2] == tv[1] && tix[2] < tix[1])) {
          float t = tv[1]; tv[1] = tv[2]; tv[2] = t;
          int ti = tix[1]; tix[1] = tix[2]; tix[2] = ti; }
        if ((tv[1] > tv[0]) || (tv[1] == tv[0] && tix[1] < tix[0])) {
          float t = tv[0]; tv[0] = tv[1]; tv[1] = t;
          int ti = tix[0]; tix[0] = tix[1]; tix[1] = ti; }
      }
    }
  }
  size_t o = (size_t)row * KSEL;
  #pragma unroll
  for (int k = 0; k < KSEL; k++) { TW[o + k] = tv[k]; TI[o + k] = tix[k]; }
}

// ---------------------------------------------------------------------------
// Neighbor aggregation. One wave per row; writes bf16 s_in / b_in.
// ---------------------------------------------------------------------------
__global__ __launch_bounds__(256)
void neighbor_kernel(const float* __restrict__ EH, const float* __restrict__ ET,
                     const float* __restrict__ TW, const int* __restrict__ TI,
                     u16* __restrict__ SINb, u16* __restrict__ BINb) {
  const int lane = threadIdx.x & 63;
  const int row = blockIdx.x * 4 + (threadIdx.x >> 6);
  const float* eh = EH + (size_t)row * DIM;
  float ehv[8];
  #pragma unroll
  for (int u = 0; u < 8; u++) ehv[u] = eh[u * 64 + lane];
  float tw[KSEL]; int ti[KSEL];
  #pragma unroll
  for (int k = 0; k < KSEL; k++) {
    tw[k] = TW[(size_t)row * KSEL + k];
    ti[k] = TI[(size_t)row * KSEL + k];
  }
  float m = tw[0];
  #pragma unroll
  for (int k = 1; k < KSEL; k++) m = fmaxf(m, tw[k]);
  float p[KSEL], ps = 0.f;
  #pragma unroll
  for (int k = 0; k < KSEL; k++) { p[k] = expf(tw[k] - m); ps += p[k]; }
  float inv = 1.f / ps;
  #pragma unroll
  for (int k = 0; k < KSEL; k++) p[k] *= inv;

  float nb[KSEL][8];
  float kaw[KSEL];
  #pragma unroll
  for (int k = 0; k < KSEL; k++) {
    const float* et = ET + (size_t)ti[k] * DIM;
    float snb = 0.f, sg = 0.f;
    #pragma unroll
    for (int u = 0; u < 8; u++) {
      float nbv = et[u * 64 + lane];
      nb[k][u] = nbv;
      float ehr = p[k] * nbv + (1.f - p[k]) * ehv[u];
      float g = tanhf(ehv[u] + ehr);
      snb += nbv; sg += g;
    }
    #pragma unroll
    for (int off = 32; off > 0; off >>= 1) {
      snb += __shfl_xor(snb, off);
      sg  += __shfl_xor(sg, off);
    }
    kaw[k] = snb * sg;
  }
  float km = kaw[0];
  #pragma unroll
  for (int k = 1; k < KSEL; k++) km = fmaxf(km, kaw[k]);
  float kp[KSEL], ks = 0.f;
  #pragma unroll
  for (int k = 0; k < KSEL; k++) { kp[k] = expf(kaw[k] - km); ks += kp[k]; }
  float kinv = 1.f / ks;
  #pragma unroll
  for (int k = 0; k < KSEL; k++) kp[k] *= kinv;

  #pragma unroll
  for (int u = 0; u < 8; u++) {
    float enh = 0.f;
    #pragma unroll
    for (int k = 0; k < KSEL; k++) enh += kp[k] * nb[k][u];
    size_t o = (size_t)row * DIM + u * 64 + lane;
    SINb[o] = f2bf(ehv[u] + enh);
    BINb[o] = f2bf(ehv[u] * enh);
  }
}

__global__ __launch_bounds__(256)
void att2_kernel(const float* __restrict__ HID, const float* __restrict__ w2,
                 const float* __restrict__ b2, float* __restrict__ ASC) {
  const int lane = threadIdx.x & 63;
  const int row = blockIdx.x * 4 + (threadIdx.x >> 6);
  float4 hv = ((const float4*)(HID + (size_t)row * 256))[lane];
  float4 wv = ((const float4*)w2)[lane];
  float s = hv.x * wv.x + hv.y * wv.y + hv.z * wv.z + hv.w * wv.w;
  #pragma unroll
  for (int off = 32; off > 0; off >>= 1) s += __shfl_xor(s, off);
  if (lane == 0) ASC[row] = s + b2[0];
}

__global__ __launch_bounds__(1024)
void areduce(const float* __restrict__ ASC, float* __restrict__ stats) {
  __shared__ float sm[1024];
  int t = threadIdx.x;
  float m = -INFINITY;
  for (int i = t; i < NROWS; i += 1024) m = fmaxf(m, ASC[i]);
  sm[t] = m; __syncthreads();
  for (int s = 512; s > 0; s >>= 1) {
    if (t < s) sm[t] = fmaxf(sm[t], sm[t + s]);
    __syncthreads();
  }
  float mx = sm[0]; __syncthreads();
  float sum = 0.f;
  for (int i = t; i < NROWS; i += 1024) sum += expf(ASC[i] - mx);
  sm[t] = sum; __syncthreads();
  for (int s = 512; s > 0; s >>= 1) {
    if (t < s) sm[t] += sm[t + s];
    __syncthreads();
  }
  if (t == 0) { stats[0] = mx; stats[1] = sm[0]; }
}

__global__ __launch_bounds__(256)
void pooled_partial(const float* __restrict__ EMB, const float* __restrict__ ASC,
                    const float* __restrict__ stats, float* __restrict__ part) {
  int col = blockIdx.x * 64 + (threadIdx.x & 63);
  int sub = threadIdx.x >> 6;
  float mx = stats[0];
  int rEnd = blockIdx.y * 512 + 512;
  float s = 0.f;
  for (int r = blockIdx.y * 512 + sub; r < rEnd; r += 4)
    s += expf(ASC[r] - mx) * EMB[(size_t)r * DIM + col];
  __shared__ float sh[4][64];
  sh[sub][threadIdx.x & 63] = s;
  __syncthreads();
  if (threadIdx.x < 64) {
    float tot = sh[0][threadIdx.x] + sh[1][threadIdx.x] +
                sh[2][threadIdx.x] + sh[3][threadIdx.x];
    part[(size_t)blockIdx.y * DIM + col] = tot;
  }
}

__global__ __launch_bounds__(512)
void final_kernel(const float* __restrict__ part, const float* __restrict__ stats,
                  const float* __restrict__ ln_g, const float* __restrict__ ln_b,
                  const float* __restrict__ fc_w, const float* __restrict__ fc_b,
                  float* __restrict__ out) {
  __shared__ float sh[512];
  int t = threadIdx.x;
  float s = 0.f;
  for (int j = 0; j < 32; j++) s += part[j * DIM + t];
  float pooled = s / stats[1];
  sh[t] = pooled; __syncthreads();
  for (int off = 256; off > 0; off >>= 1) {
    if (t < off) sh[t] += sh[t + off];
    __syncthreads();
  }
  float mu = sh[0] * (1.f / DIM); __syncthreads();
  float dv = pooled - mu;
  sh[t] = dv * dv; __syncthreads();
  for (int off = 256; off > 0; off >>= 1) {
    if (t < off) sh[t] += sh[t + off];
    __syncthreads();
  }
  float var = sh[0] * (1.f / DIM); __syncthreads();
  float normed = dv * rsqrtf(var + 1e-5f) * ln_g[t] + ln_b[t];
  sh[t] = normed * fc_w[t * 2 + 0]; __syncthreads();
  for (int off = 256; off > 0; off >>= 1) {
    if (t < off) sh[t] += sh[t + off];
    __syncthreads();
  }
  float l0 = sh[0] + fc_b[0]; __syncthreads();
  sh[t] = normed * fc_w[t * 2 + 1]; __syncthreads();
  for (int off = 256; off > 0; off >>= 1) {
    if (t < off) sh[t] += sh[t + off];
    __syncthreads();
  }
  float l1 = sh[0] + fc_b[1];
  if (t == 0) {
    float mm = fmaxf(l0, l1);
    float e0 = expf(l0 - mm), e1 = expf(l1 - mm);
    float si = 1.f / (e0 + e1);
    out[0] = l0; out[1] = l1; out[2] = e0 * si; out[3] = e1 * si;
  }
}

// ---------------------------------------------------------------------------
extern "C" void kernel_launch(void* const* d_in, const int* in_sizes, int n_in,
                              void* d_out, int out_size, void* d_ws, size_t ws_size,
                              hipStream_t stream) {
  (void)in_sizes; (void)n_in; (void)out_size; (void)ws_size;
  const float* x      = (const float*)d_in[0];
  const float* fc1_w  = (const float*)d_in[1];
  const float* fc1_b  = (const float*)d_in[2];
  const float* wh_w   = (const float*)d_in[3];
  const float* wh_b   = (const float*)d_in[4];
  const float* wt_w   = (const float*)d_in[5];
  const float* wt_b   = (const float*)d_in[6];
  const float* lin1_w = (const float*)d_in[7];
  const float* lin1_b = (const float*)d_in[8];
  const float* lin2_w = (const float*)d_in[9];
  const float* lin2_b = (const float*)d_in[10];
  const float* att1_w = (const float*)d_in[11];
  const float* att1_b = (const float*)d_in[12];
  const float* att2_w = (const float*)d_in[13];
  const float* att2_b = (const float*)d_in[14];
  const float* ln_g   = (const float*)d_in[15];
  const float* ln_b   = (const float*)d_in[16];
  const float* fc_w   = (const float*)d_in[17];
  const float* fc_b   = (const float*)d_in[18];
  float* out = (float*)d_out;

  char* ws = (char*)d_ws;
  float* B0   = (float*)(ws);                       // h0 -> HID
  float* B1   = (float*)(ws + 33554432);            // [xb] -> e_h
  float* B2   = (float*)(ws + 67108864);            // e_t -> emb
  float* TWp  = (float*)(ws + 100663296);
  int*   TIp  = (int*)  (ws + 100663296 + 1572864);
  float* TW   = (float*)(ws + 100663296 + 3145728);
  int*   TI   = (int*)  (ws + 100663296 + 3145728 + 393216);
  float* part = (float*)(ws + 100663296 + 3145728 + 786432);
  float* mean = (float*)(ws + 100663296 + 3145728 + 786432 + 65536);
  float* ascr = (float*)(ws + 100663296 + 3145728 + 786432 + 65536 + 2048);
  float* stats= (float*)(ws + 100663296 + 3145728 + 786432 + 65536 + 2048 + 65536);
  u16*   hb   = (u16*)(ws + 104732672);             // -> embb
  u16*   EHb  = (u16*)(ws + 104732672 + 16777216);  // -> sinb
  u16*   ETb  = (u16*)(ws + 104732672 + 33554432);  // -> binb
  u16*   WT   = (u16*)(ws + 104732672 + 50331648);  // transposed bf16 weights
  u16* fc1t = WT;
  u16* wht  = fc1t + 196608;
  u16* wtt  = wht + 262144;
  u16* lin1t= wtt + 262144;
  u16* lin2t= lin1t + 262144;
  u16* att1t= lin2t + 262144;
  u16* xb   = (u16*)B1;      // temp in B1 region, dead before e_h written
  u16* sinb = EHb;           // reuse after attn
  u16* binb = ETb;
  u16* embb = hb;

  // 0. input + weight conversions (bf16, weights transposed to [N][K])
  convx<<<3072, 256, 0, stream>>>(x, xb);
  wconv<<<768, 256, 0, stream>>>(fc1_w, fc1t, 384, 512);
  wconv<<<1024, 256, 0, stream>>>(wh_w, wht, 512, 512);
  wconv<<<1024, 256, 0, stream>>>(wt_w, wtt, 512, 512);
  wconv<<<1024, 256, 0, stream>>>(lin1_w, lin1t, 512, 512);
  wconv<<<1024, 256, 0, stream>>>(lin2_w, lin2t, 512, 512);
  wconv<<<512, 256, 0, stream>>>(att1_w, att1t, 512, 256);
  // 1. h0 = lrelu(x @ fc1_w + b)
  gemm_bf16<1,0,0><<<dim3(4,128), 256, 0, stream>>>(xb, fc1t, fc1_b, B0, nullptr, 1.f, 384, 512);
  // 2-4. column mean; hb = bf16((h0+mean)*0.5)
  colsum_partial<<<dim3(8,32), 256, 0, stream>>>(B0, part);
  finalize_mean<<<1, 512, 0, stream>>>(part, mean);
  h_fix_bf<<<4096, 256, 0, stream>>>(B0, mean, hb);
  // 5-6. e_h (f32 + bf16*SCALE), e_t (f32 + bf16)
  gemm_bf16<0,0,1><<<dim3(4,128), 256, 0, stream>>>(hb, wht, wh_b, B1, EHb, ATT_SCALE, 512, 512);
  gemm_bf16<0,0,1><<<dim3(4,128), 256, 0, stream>>>(hb, wtt, wt_b, B2, ETb, 1.f, 512, 512);
  // 7. fused MFMA attn-logit + top-6 per split, then merge
  attn_topk_mfma<<<512, 256, 0, stream>>>(EHb, ETb, TWp, TIp);
  topk_merge<<<64, 256, 0, stream>>>(TWp, TIp, TW, TI);
  // 8. neighbor aggregation -> bf16 s_in / b_in
  neighbor_kernel<<<4096, 256, 0, stream>>>(B1, B2, TW, TI, sinb, binb);
  // 9-10. emb = lrelu(s_in@lin1+b) + lrelu(b_in@lin2+b)  (f32 in B2 + bf16)
  gemm_bf16<1,0,0><<<dim3(4,128), 256, 0, stream>>>(sinb, lin1t, lin1_b, B2, nullptr, 1.f, 512, 512);
  gemm_bf16<1,1,1><<<dim3(4,128), 256, 0, stream>>>(binb, lin2t, lin2_b, B2, embb, 1.f, 512, 512);
  // 11. hidden = lrelu(emb@att1+b) -> B0 f32
  gemm_bf16<1,0,0><<<dim3(2,128), 256, 0, stream>>>(embb, att1t, att1_b, B0, nullptr, 1.f, 512, 256);
  // 12-15. readout
  att2_kernel<<<4096, 256, 0, stream>>>(B0, att2_w, att2_b, ascr);
  areduce<<<1, 1024, 0, stream>>>(ascr, stats);
  pooled_partial<<<dim3(8,32), 256, 0, stream>>>(B2, ascr, stats, part);
  final_kernel<<<1, 512, 0, stream>>>(part, stats, ln_g, ln_b, fc_w, fc_b, out);
}